// Round 4
// baseline (4224.043 us; speedup 1.0000x reference)
//
#include <hip/hip_runtime.h>
#include <math.h>

#define GN 48000      // G*N = 96*500
#define NPTS 500
#define KNN 20

typedef float f2 __attribute__((ext_vector_type(2)));
typedef float f4 __attribute__((ext_vector_type(4)));

__device__ __forceinline__ float fsig(float x) {
    return __builtin_amdgcn_rcpf(1.0f + __expf(-x));
}

// feats = stack([x, lat, lon], -1) reshaped (G, N, 3)
__global__ void pack_feats(const float* __restrict__ x, const float* __restrict__ la,
                           const float* __restrict__ lo, float* __restrict__ o) {
    int t = blockIdx.x * 256 + threadIdx.x;
    if (t >= GN) return;
    o[t * 3 + 0] = x[t];
    o[t * 3 + 1] = la[t];
    o[t * 3 + 2] = lo[t];
}

template <int F>
__global__ void sq_kernel(const float* __restrict__ xin, float* __restrict__ sq) {
    int t = blockIdx.x * 256 + threadIdx.x;
    if (t >= GN) return;
    float s = 0.f;
#pragma unroll
    for (int f = 0; f < F; ++f) {
        float v = xin[(size_t)t * F + f];
        s = fmaf(v, v, s);
    }
    sq[t] = s;
}

// ---- wave-per-row kNN: lane l owns candidates j = l + 64m (m=0..7) ----
// Selection: 20x { local argmin over 8 slots (ascending j, strict <) ->
// 6-step shfl_xor butterfly argmin with (d,j) lexicographic tie-break ->
// mask winner }. Matches jax.lax.top_k(-d) ordering (ties -> smaller index).

// F = 3 (scalar loads)
__global__ void __launch_bounds__(256) knn_wave3(const float* __restrict__ xin,
                                                 const float* __restrict__ sq,
                                                 int* __restrict__ idx) {
    int wv = blockIdx.x * 4 + (threadIdx.x >> 6);   // point id
    int l = threadIdx.x & 63;
    int g = wv / NPTS, i = wv - g * NPTS;
    const float* base = xin + (size_t)g * NPTS * 3;
    const float* sqg = sq + g * NPTS;
    float x0 = base[i * 3], x1 = base[i * 3 + 1], x2 = base[i * 3 + 2];
    float sqi = sqg[i];
    float d[8];
#pragma unroll
    for (int m = 0; m < 8; ++m) {
        int j = l + 64 * m;
        if (j < NPTS) {
            float dot = x0 * base[j * 3];
            dot = fmaf(x1, base[j * 3 + 1], dot);
            dot = fmaf(x2, base[j * 3 + 2], dot);
            d[m] = sqi - 2.0f * dot + sqg[j];
        } else {
            d[m] = INFINITY;
        }
    }
    int myw = 0;
    for (int s = 0; s < KNN; ++s) {
        float bd = d[0]; int bj = l;
#pragma unroll
        for (int m = 1; m < 8; ++m) {
            bool take = d[m] < bd;
            bd = take ? d[m] : bd;
            bj = take ? (l + 64 * m) : bj;
        }
#pragma unroll
        for (int st = 1; st < 64; st <<= 1) {
            float od = __shfl_xor(bd, st, 64);
            int oj = __shfl_xor(bj, st, 64);
            bool take = (od < bd) || (od == bd && oj < bj);
            bd = take ? od : bd;
            bj = take ? oj : bj;
        }
        if (l == s) myw = bj;
        int r = bj - l;
#pragma unroll
        for (int m = 0; m < 8; ++m) if (r == 64 * m) d[m] = INFINITY;
    }
    if (l < KNN) idx[(size_t)wv * KNN + l] = myw;
}

// F = 4*F4 (float4 loads, 4-way split accumulation == prior passing kernel)
template <int F4>
__global__ void __launch_bounds__(256) knn_wave4(const float* __restrict__ xin,
                                                 const float* __restrict__ sq,
                                                 int* __restrict__ idx) {
    int wv = blockIdx.x * 4 + (threadIdx.x >> 6);   // point id
    int l = threadIdx.x & 63;
    int g = wv / NPTS, i = wv - g * NPTS;
    const float4* base4 = (const float4*)(xin + (size_t)g * NPTS * (4 * F4));
    const float* sqg = sq + g * NPTS;
    float4 xi[F4];
#pragma unroll
    for (int ff = 0; ff < F4; ++ff) xi[ff] = base4[i * F4 + ff];
    float sqi = sqg[i];
    float d[8];
#pragma unroll
    for (int m = 0; m < 8; ++m) {
        int j = l + 64 * m;
        if (j < NPTS) {
            const float4* bj4 = base4 + j * F4;
            float a0 = 0.f, a1 = 0.f, a2 = 0.f, a3 = 0.f;
#pragma unroll
            for (int ff = 0; ff < F4; ++ff) {
                float4 v = bj4[ff];
                a0 = fmaf(xi[ff].x, v.x, a0);
                a1 = fmaf(xi[ff].y, v.y, a1);
                a2 = fmaf(xi[ff].z, v.z, a2);
                a3 = fmaf(xi[ff].w, v.w, a3);
            }
            float dot = (a0 + a1) + (a2 + a3);
            d[m] = sqi - 2.0f * dot + sqg[j];
        } else {
            d[m] = INFINITY;
        }
    }
    int myw = 0;
    for (int s = 0; s < KNN; ++s) {
        float bd = d[0]; int bj = l;
#pragma unroll
        for (int m = 1; m < 8; ++m) {
            bool take = d[m] < bd;
            bd = take ? d[m] : bd;
            bj = take ? (l + 64 * m) : bj;
        }
#pragma unroll
        for (int st = 1; st < 64; st <<= 1) {
            float od = __shfl_xor(bd, st, 64);
            int oj = __shfl_xor(bj, st, 64);
            bool take = (od < bd) || (od == bd && oj < bj);
            bd = take ? od : bd;
            bj = take ? oj : bj;
        }
        if (l == s) myw = bj;
        int r = bj - l;
#pragma unroll
        for (int m = 0; m < 8; ++m) if (r == 64 * m) d[m] = INFINITY;
    }
    if (l < KNN) idx[(size_t)wv * KNN + l] = myw;
}

// Wd = Wa_top - Wa_bot for each layer (hid = xi*Wd + xj*Wa_bot + ba)
__global__ void prep_wd(const float* __restrict__ W1a, const float* __restrict__ W2a,
                        const float* __restrict__ W3a, float* __restrict__ wd) {
    int t = threadIdx.x;
    for (int i = t; i < 36; i += 256) {
        int f = i / 12, h = i - f * 12;
        wd[i] = W1a[f * 12 + h] - W1a[(3 + f) * 12 + h];
    }
    for (int i = t; i < 2048; i += 256) wd[64 + i] = W2a[i] - W2a[2048 + i];
    for (int i = t; i < 2048; i += 256) wd[2112 + i] = W3a[i] - W3a[2048 + i];
}

// p[s*H+h] = x[s] . Wa_bot[:, h]   (s = global point id)
template <int F, int H>
__global__ void p_kernel(const float* __restrict__ x, const float* __restrict__ Wa,
                         float* __restrict__ p) {
    int t = blockIdx.x * 256 + threadIdx.x;
    if (t >= GN * H) return;
    int s = t / H, hh = t - s * H;
    const float* xp = x + (size_t)s * F;
    float acc = 0.f;
#pragma unroll
    for (int f = 0; f < F; ++f) acc = fmaf(xp[f], Wa[(F + f) * H + hh], acc);
    p[t] = acc;
}

// ---- edge kernels: one wave per block, grid-stride over points, no barriers ----
// NOTE: idx holds graph-LOCAL neighbor indices; p gathers use per-graph base.

// layer 1: feat in 3, H=12, C=32
__global__ void __launch_bounds__(64) edge_l1(const float* __restrict__ x, const float* __restrict__ p,
        const float* __restrict__ wdg, const float* __restrict__ Wb, const float* __restrict__ ba,
        const float* __restrict__ bb, const int* __restrict__ idx, float* __restrict__ out) {
    __shared__ float sh[16];
    int l = threadIdx.x;
    int c = l & 31;
    int hl = (l < 12) ? l : 0;
    float wb[12];
#pragma unroll
    for (int h = 0; h < 12; ++h) wb[h] = Wb[h * 32 + c];
    float bbv = bb[c];
    float bav = ba[hl];
    float wd0 = wdg[0 * 12 + hl], wd1 = wdg[1 * 12 + hl], wd2 = wdg[2 * 12 + hl];
    for (int pt = blockIdx.x; pt < GN; pt += gridDim.x) {
        int g = pt / NPTS;
        const float* pg = p + (size_t)g * NPTS * 12;
        float x0 = x[pt * 3], x1 = x[pt * 3 + 1], x2 = x[pt * 3 + 2];
        float q = fmaf(x0, wd0, bav);
        q = fmaf(x1, wd1, q);
        q = fmaf(x2, wd2, q);
        const int4* ip4 = (const int4*)(idx + (size_t)pt * KNN);
        int jj[KNN];
#pragma unroll
        for (int b = 0; b < 5; ++b) {
            int4 v = ip4[b];
            jj[b * 4] = v.x; jj[b * 4 + 1] = v.y; jj[b * 4 + 2] = v.z; jj[b * 4 + 3] = v.w;
        }
        float acc = -INFINITY;
        float pj = pg[jj[0] * 12 + hl];
#pragma unroll
        for (int n = 0; n < KNN; ++n) {
            float pjn = (n < KNN - 1) ? pg[jj[n + 1] * 12 + hl] : 0.f;
            float hid = q + pj;
            hid = (hid >= 0.f) ? hid : 0.01f * hid;
            __builtin_amdgcn_wave_barrier();
            if (l < 12) sh[l] = hid;
            __builtin_amdgcn_wave_barrier();
            float4 h0 = ((float4*)sh)[0], h1v = ((float4*)sh)[1], h2v = ((float4*)sh)[2];
            __builtin_amdgcn_wave_barrier();
            float o = bbv;
            o = fmaf(h0.x, wb[0], o); o = fmaf(h0.y, wb[1], o);
            o = fmaf(h0.z, wb[2], o); o = fmaf(h0.w, wb[3], o);
            o = fmaf(h1v.x, wb[4], o); o = fmaf(h1v.y, wb[5], o);
            o = fmaf(h1v.z, wb[6], o); o = fmaf(h1v.w, wb[7], o);
            o = fmaf(h2v.x, wb[8], o); o = fmaf(h2v.y, wb[9], o);
            o = fmaf(h2v.z, wb[10], o); o = fmaf(h2v.w, wb[11], o);
            acc = fmaxf(acc, o);
            pj = pjn;
        }
        if (l < 32) out[(size_t)pt * 32 + c] = acc;
    }
}

// layer 2: feat in 32, H=64, C=64
__global__ void __launch_bounds__(64) edge_l2(const float* __restrict__ x, const float* __restrict__ p,
        const float* __restrict__ wdg, const float* __restrict__ Wb, const float* __restrict__ ba,
        const float* __restrict__ bb, const int* __restrict__ idx, float* __restrict__ out) {
    __shared__ float sh[64];
    int l = threadIdx.x;
    float wb[64];
#pragma unroll
    for (int h = 0; h < 64; ++h) wb[h] = Wb[h * 64 + l];
    float wd[32];
#pragma unroll
    for (int f = 0; f < 32; ++f) wd[f] = wdg[f * 64 + l];
    float bav = ba[l], bbv = bb[l];
    for (int pt = blockIdx.x; pt < GN; pt += gridDim.x) {
        int g = pt / NPTS;
        const float* pg = p + (size_t)g * NPTS * 64;
        const float4* xi4 = (const float4*)(x + (size_t)pt * 32);
        float q = bav;
#pragma unroll
        for (int ff = 0; ff < 8; ++ff) {
            float4 v = xi4[ff];
            q = fmaf(v.x, wd[ff * 4 + 0], q);
            q = fmaf(v.y, wd[ff * 4 + 1], q);
            q = fmaf(v.z, wd[ff * 4 + 2], q);
            q = fmaf(v.w, wd[ff * 4 + 3], q);
        }
        const int4* ip4 = (const int4*)(idx + (size_t)pt * KNN);
        int jj[KNN];
#pragma unroll
        for (int b = 0; b < 5; ++b) {
            int4 v = ip4[b];
            jj[b * 4] = v.x; jj[b * 4 + 1] = v.y; jj[b * 4 + 2] = v.z; jj[b * 4 + 3] = v.w;
        }
        float acc = -INFINITY;
        float pj = pg[jj[0] * 64 + l];
#pragma unroll
        for (int n = 0; n < KNN; ++n) {
            float pjn = (n < KNN - 1) ? pg[jj[n + 1] * 64 + l] : 0.f;
            float hid = q + pj;
            hid = (hid >= 0.f) ? hid : 0.01f * hid;
            __builtin_amdgcn_wave_barrier();
            sh[l] = hid;
            __builtin_amdgcn_wave_barrier();
            float o = bbv;
#pragma unroll
            for (int tt = 0; tt < 16; ++tt) {
                float4 hv = ((float4*)sh)[tt];
                o = fmaf(hv.x, wb[tt * 4 + 0], o);
                o = fmaf(hv.y, wb[tt * 4 + 1], o);
                o = fmaf(hv.z, wb[tt * 4 + 2], o);
                o = fmaf(hv.w, wb[tt * 4 + 3], o);
            }
            __builtin_amdgcn_wave_barrier();
            acc = fmaxf(acc, o);
            pj = pjn;
        }
        out[(size_t)pt * 64 + l] = acc;
    }
}

// layer 3: feat in 64, H=32, C=8
__global__ void __launch_bounds__(64) edge_l3(const float* __restrict__ x, const float* __restrict__ p,
        const float* __restrict__ wdg, const float* __restrict__ Wb, const float* __restrict__ ba,
        const float* __restrict__ bb, const int* __restrict__ idx, float* __restrict__ out) {
    __shared__ float sh[32];
    int l = threadIdx.x;
    int hh = l & 31, fh = l >> 5;    // hidden idx, f-half
    int c = l & 7, hseg = l >> 3;    // out channel, h-segment (0..7)
    float wd[32];
#pragma unroll
    for (int f2_ = 0; f2_ < 32; ++f2_) wd[f2_] = wdg[(fh * 32 + f2_) * 32 + hh];
    float wb[4];
#pragma unroll
    for (int e = 0; e < 4; ++e) wb[e] = Wb[(hseg * 4 + e) * 8 + c];
    float bav = ba[hh], bbv = bb[c];
    for (int pt = blockIdx.x; pt < GN; pt += gridDim.x) {
        int g = pt / NPTS;
        const float* pg = p + (size_t)g * NPTS * 32;
        const float4* xi4 = (const float4*)(x + (size_t)pt * 64);
        float qp = 0.f;
#pragma unroll
        for (int ff = 0; ff < 8; ++ff) {
            float4 v = xi4[fh * 8 + ff];
            qp = fmaf(v.x, wd[ff * 4 + 0], qp);
            qp = fmaf(v.y, wd[ff * 4 + 1], qp);
            qp = fmaf(v.z, wd[ff * 4 + 2], qp);
            qp = fmaf(v.w, wd[ff * 4 + 3], qp);
        }
        float q = bav + qp + __shfl_xor(qp, 32, 64);
        const int4* ip4 = (const int4*)(idx + (size_t)pt * KNN);
        int jj[KNN];
#pragma unroll
        for (int b = 0; b < 5; ++b) {
            int4 v = ip4[b];
            jj[b * 4] = v.x; jj[b * 4 + 1] = v.y; jj[b * 4 + 2] = v.z; jj[b * 4 + 3] = v.w;
        }
        float acc = -INFINITY;
        float pj = pg[jj[0] * 32 + hh];
#pragma unroll
        for (int n = 0; n < KNN; ++n) {
            float pjn = (n < KNN - 1) ? pg[jj[n + 1] * 32 + hh] : 0.f;
            float hid = q + pj;
            hid = (hid >= 0.f) ? hid : 0.01f * hid;
            __builtin_amdgcn_wave_barrier();
            if (l < 32) sh[l] = hid;
            __builtin_amdgcn_wave_barrier();
            float4 hv = ((float4*)sh)[hseg];
            __builtin_amdgcn_wave_barrier();
            float o = hv.x * wb[0];
            o = fmaf(hv.y, wb[1], o);
            o = fmaf(hv.z, wb[2], o);
            o = fmaf(hv.w, wb[3], o);
            o += __shfl_xor(o, 8, 64);
            o += __shfl_xor(o, 16, 64);
            o += __shfl_xor(o, 32, 64);
            acc = fmaxf(acc, o + bbv);
            pj = pjn;
        }
        if (l < 8) out[(size_t)pt * 8 + c] = acc;
    }
}

// ut[j][s] = bih[j] + bhh[j] + seq[s] . Wih[j,:]   (transposed: per-gate contiguous in s)
__global__ void lstm_pre(const float* __restrict__ h3, const float* __restrict__ Wih,
                         const float* __restrict__ bih, const float* __restrict__ bhh,
                         float* __restrict__ ut) {
    int t = blockIdx.x * 256 + threadIdx.x;
    if (t >= 4000 * 128) return;
    int j = t / 4000, s = t - j * 4000;
    int b = s / 500, n = s - b * 500;
    const float* xp = h3 + ((size_t)(b * 12 + 11) * 500 + n) * 8;
    float acc = bih[j] + bhh[j];
#pragma unroll
    for (int f = 0; f < 8; ++f) acc = fmaf(xp[f], Wih[j * 8 + f], acc);
    ut[(size_t)j * 4000 + s] = acc;
}

// single-wave barrier-free LSTM; lane l owns gates l and l+64.
__global__ void __launch_bounds__(64) lstm_seq(const float* __restrict__ ut,
                                               const float* __restrict__ Whh,
                                               float* __restrict__ outh_t) {
    __shared__ float sh[64];
    int l = threadIdx.x;
    f2 w0[16], w1[16];
#pragma unroll
    for (int k = 0; k < 16; ++k) {
        w0[k] = f2{Whh[l * 32 + 2 * k], Whh[l * 32 + 2 * k + 1]};
        w1[k] = f2{Whh[(l + 64) * 32 + 2 * k], Whh[(l + 64) * 32 + 2 * k + 1]};
    }
    bool lo = (l < 32);
    float m2 = lo ? 2.0f : 1.0f;     // tanh-from-sigmoid fixup: lane<32 needs tanh(g1)
    float a2 = lo ? -1.0f : 0.0f;
    float c = 0.f;
    sh[l] = 0.f;                     // h = 0
    const float* u0p = ut + (size_t)l * 4000;
    const float* u1p = ut + (size_t)(l + 64) * 4000;
    f4 ua = *(const f4*)(u0p);
    f4 ub = *(const f4*)(u1p);
    f4 na = ua, nb = ub;
    const f2* shv = (const f2*)sh;

#define LSTM_STEP(U0, U1, HOUT) {                                       \
        f2 acc0 = f2{(U0), 0.f}, acc1 = f2{(U1), 0.f};                  \
        _Pragma("unroll")                                               \
        for (int k = 0; k < 16; ++k) {                                  \
            f2 hp = shv[k];                                             \
            acc0 = __builtin_elementwise_fma(w0[k], hp, acc0);          \
            acc1 = __builtin_elementwise_fma(w1[k], hp, acc1);          \
        }                                                               \
        float g0 = acc0.x + acc0.y, g1 = acc1.x + acc1.y;               \
        float s0 = fsig(g0);                                            \
        float t1 = fmaf(fsig(m2 * g1), m2, a2);                         \
        float part = s0 * t1;                                           \
        float sf = __shfl_xor(s0, 32, 64);                              \
        float so = __shfl_xor(t1, 32, 64);                              \
        c = fmaf(sf, c, part);                                          \
        float tc = fmaf(fsig(c + c), 2.f, -1.f);                        \
        float h = so * tc;                                              \
        __builtin_amdgcn_wave_barrier();                                \
        sh[l] = h;                                                      \
        __builtin_amdgcn_wave_barrier();                                \
        HOUT = h;                                                       \
    }

    for (int s4 = 0; s4 < 4000; s4 += 4) {
        if (s4 + 4 < 4000) {
            na = *(const f4*)(u0p + s4 + 4);
            nb = *(const f4*)(u1p + s4 + 4);
        }
        f4 hq;
        LSTM_STEP(ua.x, ub.x, hq.x);
        LSTM_STEP(ua.y, ub.y, hq.y);
        LSTM_STEP(ua.z, ub.z, hq.z);
        LSTM_STEP(ua.w, ub.w, hq.w);
        if (lo) *(f4*)(outh_t + (size_t)l * 4000 + s4) = hq;
        ua = na; ub = nb;
    }
#undef LSTM_STEP
}

// emb = [out(32), weather[s%8, 11, :](8), time_enc[s%8, 11, :](8)] @ Wl + bl
__global__ void final_pred(const float* __restrict__ outh_t, const float* __restrict__ wth,
                           const float* __restrict__ ten, const float* __restrict__ Wl,
                           const float* __restrict__ bl, float* __restrict__ pred) {
    int s = blockIdx.x * 256 + threadIdx.x;
    if (s >= 4000) return;
    float a = bl[0];
#pragma unroll
    for (int k = 0; k < 32; ++k) a = fmaf(outh_t[(size_t)k * 4000 + s], Wl[k], a);
    int r = s & 7;   // s % 8, replicating jnp.tile row indexing
#pragma unroll
    for (int k = 0; k < 8; ++k) a = fmaf(wth[(r * 12 + 11) * 8 + k], Wl[32 + k], a);
#pragma unroll
    for (int k = 0; k < 8; ++k) a = fmaf(ten[(r * 12 + 11) * 8 + k], Wl[40 + k], a);
    pred[s] = a;
}

extern "C" void kernel_launch(void* const* d_in, const int* in_sizes, int n_in,
                              void* d_out, int out_size, void* d_ws, size_t ws_size,
                              hipStream_t stream) {
    const float* x   = (const float*)d_in[0];
    const float* lat = (const float*)d_in[1];
    const float* lon = (const float*)d_in[2];
    const float* wth = (const float*)d_in[3];
    const float* ten = (const float*)d_in[4];
    const float* W1a = (const float*)d_in[5];
    const float* b1a = (const float*)d_in[6];
    const float* W1b = (const float*)d_in[7];
    const float* b1b = (const float*)d_in[8];
    const float* W2a = (const float*)d_in[9];
    const float* b2a = (const float*)d_in[10];
    const float* W2b = (const float*)d_in[11];
    const float* b2b = (const float*)d_in[12];
    const float* W3a = (const float*)d_in[13];
    const float* b3a = (const float*)d_in[14];
    const float* W3b = (const float*)d_in[15];
    const float* b3b = (const float*)d_in[16];
    const float* Wih = (const float*)d_in[17];
    const float* Whh = (const float*)d_in[18];
    const float* bih = (const float*)d_in[19];
    const float* bhh = (const float*)d_in[20];
    const float* Wl  = (const float*)d_in[21];
    const float* bl  = (const float*)d_in[22];

    float* ws = (float*)d_ws;
    float* feats0 = ws;                    // 144000
    float* h1     = ws + 144000;           // 1536000
    float* h2     = ws + 1680000;          // 3072000
    float* h3     = ws + 4752000;          // 384000
    float* sqb    = ws + 5136000;          // 48000
    float* ut     = ws + 5184000;          // 512000 (transposed u: [128][4000])
    float* outh   = ws + 5696000;          // 128000 (transposed: [32][4000])
    int*   idx    = (int*)(ws + 5824000);  // 960000 ints
    float* pbuf   = ws + 6784000;          // 3072000 (max layer: 48000*64)
    float* wdbuf  = ws + 9856000;          // 4160: Wd1 @0 (36), Wd2 @64 (2048), Wd3 @2112 (2048)

    const int nb = (GN + 255) / 256;   // 188
    const int KB = GN / 4;             // 12000 blocks, one wave per point
    const int EB = 3072;               // edge-kernel grid (grid-stride over points)

    pack_feats<<<nb, 256, 0, stream>>>(x, lat, lon, feats0);
    prep_wd<<<1, 256, 0, stream>>>(W1a, W2a, W3a, wdbuf);

    // layer 1: 3 -> (6,12,32)
    sq_kernel<3><<<nb, 256, 0, stream>>>(feats0, sqb);
    knn_wave3<<<KB, 256, 0, stream>>>(feats0, sqb, idx);
    p_kernel<3, 12><<<(GN * 12 + 255) / 256, 256, 0, stream>>>(feats0, W1a, pbuf);
    edge_l1<<<EB, 64, 0, stream>>>(feats0, pbuf, wdbuf, W1b, b1a, b1b, idx, h1);

    // layer 2: 32 -> (64,64,64)
    sq_kernel<32><<<nb, 256, 0, stream>>>(h1, sqb);
    knn_wave4<8><<<KB, 256, 0, stream>>>(h1, sqb, idx);
    p_kernel<32, 64><<<(GN * 64 + 255) / 256, 256, 0, stream>>>(h1, W2a, pbuf);
    edge_l2<<<EB, 64, 0, stream>>>(h1, pbuf, wdbuf + 64, W2b, b2a, b2b, idx, h2);

    // layer 3: 64 -> (128,32,8)
    sq_kernel<64><<<nb, 256, 0, stream>>>(h2, sqb);
    knn_wave4<16><<<KB, 256, 0, stream>>>(h2, sqb, idx);
    p_kernel<64, 32><<<(GN * 32 + 255) / 256, 256, 0, stream>>>(h2, W3a, pbuf);
    edge_l3<<<EB, 64, 0, stream>>>(h2, pbuf, wdbuf + 2112, W3b, b3a, b3b, idx, h3);

    // LSTM (only batch column 11 matters)
    lstm_pre<<<(4000 * 128 + 255) / 256, 256, 0, stream>>>(h3, Wih, bih, bhh, ut);
    lstm_seq<<<1, 64, 0, stream>>>(ut, Whh, outh);

    final_pred<<<(4000 + 255) / 256, 256, 0, stream>>>(outh, wth, ten, Wl, bl, (float*)d_out);
}

// Round 5
// 4140.786 us; speedup vs baseline: 1.0201x; 1.0201x over previous
//
#include <hip/hip_runtime.h>
#include <math.h>

#define GN 48000      // G*N = 96*500
#define NPTS 500
#define KNN 20

typedef float f2 __attribute__((ext_vector_type(2)));
typedef float f4 __attribute__((ext_vector_type(4)));

__device__ __forceinline__ float fsig(float x) {
    return __builtin_amdgcn_rcpf(1.0f + __expf(-x));
}

// feats = stack([x, lat, lon], -1) reshaped (G, N, 3)
__global__ void pack_feats(const float* __restrict__ x, const float* __restrict__ la,
                           const float* __restrict__ lo, float* __restrict__ o) {
    int t = blockIdx.x * 256 + threadIdx.x;
    if (t >= GN) return;
    o[t * 3 + 0] = x[t];
    o[t * 3 + 1] = la[t];
    o[t * 3 + 2] = lo[t];
}

template <int F>
__global__ void sq_kernel(const float* __restrict__ xin, float* __restrict__ sq) {
    int t = blockIdx.x * 256 + threadIdx.x;
    if (t >= GN) return;
    float s = 0.f;
#pragma unroll
    for (int f = 0; f < F; ++f) {
        float v = xin[(size_t)t * F + f];
        s = fmaf(v, v, s);
    }
    sq[t] = s;
}

// ---- wave-per-row kNN: lane l owns candidates j = l + 64m (m=0..7) ----
// Selection: 20x { local argmin over 8 slots (ascending j, strict <) ->
// 6-step shfl_xor butterfly argmin with (d,j) lexicographic tie-break ->
// mask winner }. Matches jax.lax.top_k(-d) ordering (ties -> smaller index).
// XCD swizzle: 12000 blocks, 12000 % 8 == 0 -> bijective chunked remap so
// each XCD's L2 serves a contiguous run of graphs.

__device__ __forceinline__ int swz_block(int bid) {
    return (bid & 7) * 1500 + (bid >> 3);   // 12000/8 = 1500
}

// F = 3 (scalar loads)
__global__ void __launch_bounds__(256) knn_wave3(const float* __restrict__ xin,
                                                 const float* __restrict__ sq,
                                                 int* __restrict__ idx) {
    int wv = swz_block(blockIdx.x) * 4 + (threadIdx.x >> 6);   // point id
    int l = threadIdx.x & 63;
    int g = wv / NPTS, i = wv - g * NPTS;
    const float* base = xin + (size_t)g * NPTS * 3;
    const float* sqg = sq + g * NPTS;
    float x0 = base[i * 3], x1 = base[i * 3 + 1], x2 = base[i * 3 + 2];
    float sqi = sqg[i];
    float d[8];
#pragma unroll
    for (int m = 0; m < 8; ++m) {
        int j = l + 64 * m;
        if (j < NPTS) {
            float dot = x0 * base[j * 3];
            dot = fmaf(x1, base[j * 3 + 1], dot);
            dot = fmaf(x2, base[j * 3 + 2], dot);
            d[m] = sqi - 2.0f * dot + sqg[j];
        } else {
            d[m] = INFINITY;
        }
        __builtin_amdgcn_sched_barrier(0);   // bound load liveness (no spill)
    }
    int myw = 0;
    for (int s = 0; s < KNN; ++s) {
        float bd = d[0]; int bj = l;
#pragma unroll
        for (int m = 1; m < 8; ++m) {
            bool take = d[m] < bd;
            bd = take ? d[m] : bd;
            bj = take ? (l + 64 * m) : bj;
        }
#pragma unroll
        for (int st = 1; st < 64; st <<= 1) {
            float od = __shfl_xor(bd, st, 64);
            int oj = __shfl_xor(bj, st, 64);
            bool take = (od < bd) || (od == bd && oj < bj);
            bd = take ? od : bd;
            bj = take ? oj : bj;
        }
        if (l == s) myw = bj;
        int r = bj - l;
#pragma unroll
        for (int m = 0; m < 8; ++m) if (r == 64 * m) d[m] = INFINITY;
    }
    if (l < KNN) idx[(size_t)wv * KNN + l] = myw;
}

// F = 4*F4 (float4 loads, 4-way split accumulation == prior passing kernel)
template <int F4>
__global__ void __launch_bounds__(256) knn_wave4(const float* __restrict__ xin,
                                                 const float* __restrict__ sq,
                                                 int* __restrict__ idx) {
    int wv = swz_block(blockIdx.x) * 4 + (threadIdx.x >> 6);   // point id
    int l = threadIdx.x & 63;
    int g = wv / NPTS, i = wv - g * NPTS;
    const float4* base4 = (const float4*)(xin + (size_t)g * NPTS * (4 * F4));
    const float* sqg = sq + g * NPTS;
    float4 xi[F4];
#pragma unroll
    for (int ff = 0; ff < F4; ++ff) xi[ff] = base4[i * F4 + ff];
    float sqi = sqg[i];
    float d[8];
#pragma unroll
    for (int m = 0; m < 8; ++m) {
        int j = l + 64 * m;
        if (j < NPTS) {
            const float4* bj4 = base4 + j * F4;
            float a0 = 0.f, a1 = 0.f, a2 = 0.f, a3 = 0.f;
#pragma unroll
            for (int ff = 0; ff < F4; ++ff) {
                float4 v = bj4[ff];
                a0 = fmaf(xi[ff].x, v.x, a0);
                a1 = fmaf(xi[ff].y, v.y, a1);
                a2 = fmaf(xi[ff].z, v.z, a2);
                a3 = fmaf(xi[ff].w, v.w, a3);
            }
            float dot = (a0 + a1) + (a2 + a3);
            d[m] = sqi - 2.0f * dot + sqg[j];
        } else {
            d[m] = INFINITY;
        }
        __builtin_amdgcn_sched_barrier(0);   // bound load liveness (no spill)
    }
    int myw = 0;
    for (int s = 0; s < KNN; ++s) {
        float bd = d[0]; int bj = l;
#pragma unroll
        for (int m = 1; m < 8; ++m) {
            bool take = d[m] < bd;
            bd = take ? d[m] : bd;
            bj = take ? (l + 64 * m) : bj;
        }
#pragma unroll
        for (int st = 1; st < 64; st <<= 1) {
            float od = __shfl_xor(bd, st, 64);
            int oj = __shfl_xor(bj, st, 64);
            bool take = (od < bd) || (od == bd && oj < bj);
            bd = take ? od : bd;
            bj = take ? oj : bj;
        }
        if (l == s) myw = bj;
        int r = bj - l;
#pragma unroll
        for (int m = 0; m < 8; ++m) if (r == 64 * m) d[m] = INFINITY;
    }
    if (l < KNN) idx[(size_t)wv * KNN + l] = myw;
}

// Wd = Wa_top - Wa_bot for each layer (hid = xi*Wd + xj*Wa_bot + ba)
__global__ void prep_wd(const float* __restrict__ W1a, const float* __restrict__ W2a,
                        const float* __restrict__ W3a, float* __restrict__ wd) {
    int t = threadIdx.x;
    for (int i = t; i < 36; i += 256) {
        int f = i / 12, h = i - f * 12;
        wd[i] = W1a[f * 12 + h] - W1a[(3 + f) * 12 + h];
    }
    for (int i = t; i < 2048; i += 256) wd[64 + i] = W2a[i] - W2a[2048 + i];
    for (int i = t; i < 2048; i += 256) wd[2112 + i] = W3a[i] - W3a[2048 + i];
}

// p[s*H+h] = x[s] . Wa_bot[:, h]   (s = global point id)
template <int F, int H>
__global__ void p_kernel(const float* __restrict__ x, const float* __restrict__ Wa,
                         float* __restrict__ p) {
    int t = blockIdx.x * 256 + threadIdx.x;
    if (t >= GN * H) return;
    int s = t / H, hh = t - s * H;
    const float* xp = x + (size_t)s * F;
    float acc = 0.f;
#pragma unroll
    for (int f = 0; f < F; ++f) acc = fmaf(xp[f], Wa[(F + f) * H + hh], acc);
    p[t] = acc;
}

// ---- edge kernels: one wave per block, grid-stride over points, no barriers ----
// NOTE: idx holds graph-LOCAL neighbor indices; p gathers use per-graph base.

// layer 1: feat in 3, H=12, C=32
__global__ void __launch_bounds__(64) edge_l1(const float* __restrict__ x, const float* __restrict__ p,
        const float* __restrict__ wdg, const float* __restrict__ Wb, const float* __restrict__ ba,
        const float* __restrict__ bb, const int* __restrict__ idx, float* __restrict__ out) {
    __shared__ float sh[16];
    int l = threadIdx.x;
    int c = l & 31;
    int hl = (l < 12) ? l : 0;
    float wb[12];
#pragma unroll
    for (int h = 0; h < 12; ++h) wb[h] = Wb[h * 32 + c];
    float bbv = bb[c];
    float bav = ba[hl];
    float wd0 = wdg[0 * 12 + hl], wd1 = wdg[1 * 12 + hl], wd2 = wdg[2 * 12 + hl];
    for (int pt = blockIdx.x; pt < GN; pt += gridDim.x) {
        int g = pt / NPTS;
        const float* pg = p + (size_t)g * NPTS * 12;
        float x0 = x[pt * 3], x1 = x[pt * 3 + 1], x2 = x[pt * 3 + 2];
        float q = fmaf(x0, wd0, bav);
        q = fmaf(x1, wd1, q);
        q = fmaf(x2, wd2, q);
        const int4* ip4 = (const int4*)(idx + (size_t)pt * KNN);
        int jj[KNN];
#pragma unroll
        for (int b = 0; b < 5; ++b) {
            int4 v = ip4[b];
            jj[b * 4] = v.x; jj[b * 4 + 1] = v.y; jj[b * 4 + 2] = v.z; jj[b * 4 + 3] = v.w;
        }
        float acc = -INFINITY;
        float pj = pg[jj[0] * 12 + hl];
#pragma unroll
        for (int n = 0; n < KNN; ++n) {
            float pjn = (n < KNN - 1) ? pg[jj[n + 1] * 12 + hl] : 0.f;
            float hid = q + pj;
            hid = (hid >= 0.f) ? hid : 0.01f * hid;
            __builtin_amdgcn_wave_barrier();
            if (l < 12) sh[l] = hid;
            __builtin_amdgcn_wave_barrier();
            float4 h0 = ((float4*)sh)[0], h1v = ((float4*)sh)[1], h2v = ((float4*)sh)[2];
            __builtin_amdgcn_wave_barrier();
            float o = bbv;
            o = fmaf(h0.x, wb[0], o); o = fmaf(h0.y, wb[1], o);
            o = fmaf(h0.z, wb[2], o); o = fmaf(h0.w, wb[3], o);
            o = fmaf(h1v.x, wb[4], o); o = fmaf(h1v.y, wb[5], o);
            o = fmaf(h1v.z, wb[6], o); o = fmaf(h1v.w, wb[7], o);
            o = fmaf(h2v.x, wb[8], o); o = fmaf(h2v.y, wb[9], o);
            o = fmaf(h2v.z, wb[10], o); o = fmaf(h2v.w, wb[11], o);
            acc = fmaxf(acc, o);
            pj = pjn;
        }
        if (l < 32) out[(size_t)pt * 32 + c] = acc;
    }
}

// layer 2: feat in 32, H=64, C=64
__global__ void __launch_bounds__(64) edge_l2(const float* __restrict__ x, const float* __restrict__ p,
        const float* __restrict__ wdg, const float* __restrict__ Wb, const float* __restrict__ ba,
        const float* __restrict__ bb, const int* __restrict__ idx, float* __restrict__ out) {
    __shared__ float sh[64];
    int l = threadIdx.x;
    float wb[64];
#pragma unroll
    for (int h = 0; h < 64; ++h) wb[h] = Wb[h * 64 + l];
    float wd[32];
#pragma unroll
    for (int f = 0; f < 32; ++f) wd[f] = wdg[f * 64 + l];
    float bav = ba[l], bbv = bb[l];
    for (int pt = blockIdx.x; pt < GN; pt += gridDim.x) {
        int g = pt / NPTS;
        const float* pg = p + (size_t)g * NPTS * 64;
        const float4* xi4 = (const float4*)(x + (size_t)pt * 32);
        float q = bav;
#pragma unroll
        for (int ff = 0; ff < 8; ++ff) {
            float4 v = xi4[ff];
            q = fmaf(v.x, wd[ff * 4 + 0], q);
            q = fmaf(v.y, wd[ff * 4 + 1], q);
            q = fmaf(v.z, wd[ff * 4 + 2], q);
            q = fmaf(v.w, wd[ff * 4 + 3], q);
        }
        const int4* ip4 = (const int4*)(idx + (size_t)pt * KNN);
        int jj[KNN];
#pragma unroll
        for (int b = 0; b < 5; ++b) {
            int4 v = ip4[b];
            jj[b * 4] = v.x; jj[b * 4 + 1] = v.y; jj[b * 4 + 2] = v.z; jj[b * 4 + 3] = v.w;
        }
        float acc = -INFINITY;
        float pj = pg[jj[0] * 64 + l];
#pragma unroll
        for (int n = 0; n < KNN; ++n) {
            float pjn = (n < KNN - 1) ? pg[jj[n + 1] * 64 + l] : 0.f;
            float hid = q + pj;
            hid = (hid >= 0.f) ? hid : 0.01f * hid;
            __builtin_amdgcn_wave_barrier();
            sh[l] = hid;
            __builtin_amdgcn_wave_barrier();
            float o = bbv;
#pragma unroll
            for (int tt = 0; tt < 16; ++tt) {
                float4 hv = ((float4*)sh)[tt];
                o = fmaf(hv.x, wb[tt * 4 + 0], o);
                o = fmaf(hv.y, wb[tt * 4 + 1], o);
                o = fmaf(hv.z, wb[tt * 4 + 2], o);
                o = fmaf(hv.w, wb[tt * 4 + 3], o);
            }
            __builtin_amdgcn_wave_barrier();
            acc = fmaxf(acc, o);
            pj = pjn;
        }
        out[(size_t)pt * 64 + l] = acc;
    }
}

// layer 3: feat in 64, H=32, C=8
__global__ void __launch_bounds__(64) edge_l3(const float* __restrict__ x, const float* __restrict__ p,
        const float* __restrict__ wdg, const float* __restrict__ Wb, const float* __restrict__ ba,
        const float* __restrict__ bb, const int* __restrict__ idx, float* __restrict__ out) {
    __shared__ float sh[32];
    int l = threadIdx.x;
    int hh = l & 31, fh = l >> 5;    // hidden idx, f-half
    int c = l & 7, hseg = l >> 3;    // out channel, h-segment (0..7)
    float wd[32];
#pragma unroll
    for (int f2_ = 0; f2_ < 32; ++f2_) wd[f2_] = wdg[(fh * 32 + f2_) * 32 + hh];
    float wb[4];
#pragma unroll
    for (int e = 0; e < 4; ++e) wb[e] = Wb[(hseg * 4 + e) * 8 + c];
    float bav = ba[hh], bbv = bb[c];
    for (int pt = blockIdx.x; pt < GN; pt += gridDim.x) {
        int g = pt / NPTS;
        const float* pg = p + (size_t)g * NPTS * 32;
        const float4* xi4 = (const float4*)(x + (size_t)pt * 64);
        float qp = 0.f;
#pragma unroll
        for (int ff = 0; ff < 8; ++ff) {
            float4 v = xi4[fh * 8 + ff];
            qp = fmaf(v.x, wd[ff * 4 + 0], qp);
            qp = fmaf(v.y, wd[ff * 4 + 1], qp);
            qp = fmaf(v.z, wd[ff * 4 + 2], qp);
            qp = fmaf(v.w, wd[ff * 4 + 3], qp);
        }
        float q = bav + qp + __shfl_xor(qp, 32, 64);
        const int4* ip4 = (const int4*)(idx + (size_t)pt * KNN);
        int jj[KNN];
#pragma unroll
        for (int b = 0; b < 5; ++b) {
            int4 v = ip4[b];
            jj[b * 4] = v.x; jj[b * 4 + 1] = v.y; jj[b * 4 + 2] = v.z; jj[b * 4 + 3] = v.w;
        }
        float acc = -INFINITY;
        float pj = pg[jj[0] * 32 + hh];
#pragma unroll
        for (int n = 0; n < KNN; ++n) {
            float pjn = (n < KNN - 1) ? pg[jj[n + 1] * 32 + hh] : 0.f;
            float hid = q + pj;
            hid = (hid >= 0.f) ? hid : 0.01f * hid;
            __builtin_amdgcn_wave_barrier();
            if (l < 32) sh[l] = hid;
            __builtin_amdgcn_wave_barrier();
            float4 hv = ((float4*)sh)[hseg];
            __builtin_amdgcn_wave_barrier();
            float o = hv.x * wb[0];
            o = fmaf(hv.y, wb[1], o);
            o = fmaf(hv.z, wb[2], o);
            o = fmaf(hv.w, wb[3], o);
            o += __shfl_xor(o, 8, 64);
            o += __shfl_xor(o, 16, 64);
            o += __shfl_xor(o, 32, 64);
            acc = fmaxf(acc, o + bbv);
            pj = pjn;
        }
        if (l < 8) out[(size_t)pt * 8 + c] = acc;
    }
}

// ut[j][s] = bih[j] + bhh[j] + seq[s] . Wih[j,:]   (transposed: per-gate contiguous in s)
__global__ void lstm_pre(const float* __restrict__ h3, const float* __restrict__ Wih,
                         const float* __restrict__ bih, const float* __restrict__ bhh,
                         float* __restrict__ ut) {
    int t = blockIdx.x * 256 + threadIdx.x;
    if (t >= 4000 * 128) return;
    int j = t / 4000, s = t - j * 4000;
    int b = s / 500, n = s - b * 500;
    const float* xp = h3 + ((size_t)(b * 12 + 11) * 500 + n) * 8;
    float acc = bih[j] + bhh[j];
#pragma unroll
    for (int f = 0; f < 8; ++f) acc = fmaf(xp[f], Wih[j * 8 + f], acc);
    ut[(size_t)j * 4000 + s] = acc;
}

// single-wave barrier-free LSTM; lane l owns gates l and l+64.
__global__ void __launch_bounds__(64) lstm_seq(const float* __restrict__ ut,
                                               const float* __restrict__ Whh,
                                               float* __restrict__ outh_t) {
    __shared__ float sh[64];
    int l = threadIdx.x;
    f2 w0[16], w1[16];
#pragma unroll
    for (int k = 0; k < 16; ++k) {
        w0[k] = f2{Whh[l * 32 + 2 * k], Whh[l * 32 + 2 * k + 1]};
        w1[k] = f2{Whh[(l + 64) * 32 + 2 * k], Whh[(l + 64) * 32 + 2 * k + 1]};
    }
    bool lo = (l < 32);
    float m2 = lo ? 2.0f : 1.0f;     // tanh-from-sigmoid fixup: lane<32 needs tanh(g1)
    float a2 = lo ? -1.0f : 0.0f;
    float c = 0.f;
    sh[l] = 0.f;                     // h = 0
    const float* u0p = ut + (size_t)l * 4000;
    const float* u1p = ut + (size_t)(l + 64) * 4000;
    f4 ua = *(const f4*)(u0p);
    f4 ub = *(const f4*)(u1p);
    f4 na = ua, nb = ub;
    const f2* shv = (const f2*)sh;

#define LSTM_STEP(U0, U1, HOUT) {                                       \
        f2 acc0 = f2{(U0), 0.f}, acc1 = f2{(U1), 0.f};                  \
        _Pragma("unroll")                                               \
        for (int k = 0; k < 16; ++k) {                                  \
            f2 hp = shv[k];                                             \
            acc0 = __builtin_elementwise_fma(w0[k], hp, acc0);          \
            acc1 = __builtin_elementwise_fma(w1[k], hp, acc1);          \
        }                                                               \
        float g0 = acc0.x + acc0.y, g1 = acc1.x + acc1.y;               \
        float s0 = fsig(g0);                                            \
        float t1 = fmaf(fsig(m2 * g1), m2, a2);                         \
        float part = s0 * t1;                                           \
        float sf = __shfl_xor(s0, 32, 64);                              \
        float so = __shfl_xor(t1, 32, 64);                              \
        c = fmaf(sf, c, part);                                          \
        float tc = fmaf(fsig(c + c), 2.f, -1.f);                        \
        float h = so * tc;                                              \
        __builtin_amdgcn_wave_barrier();                                \
        sh[l] = h;                                                      \
        __builtin_amdgcn_wave_barrier();                                \
        HOUT = h;                                                       \
    }

    for (int s4 = 0; s4 < 4000; s4 += 4) {
        if (s4 + 4 < 4000) {
            na = *(const f4*)(u0p + s4 + 4);
            nb = *(const f4*)(u1p + s4 + 4);
        }
        f4 hq;
        LSTM_STEP(ua.x, ub.x, hq.x);
        LSTM_STEP(ua.y, ub.y, hq.y);
        LSTM_STEP(ua.z, ub.z, hq.z);
        LSTM_STEP(ua.w, ub.w, hq.w);
        if (lo) *(f4*)(outh_t + (size_t)l * 4000 + s4) = hq;
        ua = na; ub = nb;
    }
#undef LSTM_STEP
}

// emb = [out(32), weather[s%8, 11, :](8), time_enc[s%8, 11, :](8)] @ Wl + bl
__global__ void final_pred(const float* __restrict__ outh_t, const float* __restrict__ wth,
                           const float* __restrict__ ten, const float* __restrict__ Wl,
                           const float* __restrict__ bl, float* __restrict__ pred) {
    int s = blockIdx.x * 256 + threadIdx.x;
    if (s >= 4000) return;
    float a = bl[0];
#pragma unroll
    for (int k = 0; k < 32; ++k) a = fmaf(outh_t[(size_t)k * 4000 + s], Wl[k], a);
    int r = s & 7;   // s % 8, replicating jnp.tile row indexing
#pragma unroll
    for (int k = 0; k < 8; ++k) a = fmaf(wth[(r * 12 + 11) * 8 + k], Wl[32 + k], a);
#pragma unroll
    for (int k = 0; k < 8; ++k) a = fmaf(ten[(r * 12 + 11) * 8 + k], Wl[40 + k], a);
    pred[s] = a;
}

extern "C" void kernel_launch(void* const* d_in, const int* in_sizes, int n_in,
                              void* d_out, int out_size, void* d_ws, size_t ws_size,
                              hipStream_t stream) {
    const float* x   = (const float*)d_in[0];
    const float* lat = (const float*)d_in[1];
    const float* lon = (const float*)d_in[2];
    const float* wth = (const float*)d_in[3];
    const float* ten = (const float*)d_in[4];
    const float* W1a = (const float*)d_in[5];
    const float* b1a = (const float*)d_in[6];
    const float* W1b = (const float*)d_in[7];
    const float* b1b = (const float*)d_in[8];
    const float* W2a = (const float*)d_in[9];
    const float* b2a = (const float*)d_in[10];
    const float* W2b = (const float*)d_in[11];
    const float* b2b = (const float*)d_in[12];
    const float* W3a = (const float*)d_in[13];
    const float* b3a = (const float*)d_in[14];
    const float* W3b = (const float*)d_in[15];
    const float* b3b = (const float*)d_in[16];
    const float* Wih = (const float*)d_in[17];
    const float* Whh = (const float*)d_in[18];
    const float* bih = (const float*)d_in[19];
    const float* bhh = (const float*)d_in[20];
    const float* Wl  = (const float*)d_in[21];
    const float* bl  = (const float*)d_in[22];

    float* ws = (float*)d_ws;
    float* feats0 = ws;                    // 144000
    float* h1     = ws + 144000;           // 1536000
    float* h2     = ws + 1680000;          // 3072000
    float* h3     = ws + 4752000;          // 384000
    float* sqb    = ws + 5136000;          // 48000
    float* ut     = ws + 5184000;          // 512000 (transposed u: [128][4000])
    float* outh   = ws + 5696000;          // 128000 (transposed: [32][4000])
    int*   idx    = (int*)(ws + 5824000);  // 960000 ints
    float* pbuf   = ws + 6784000;          // 3072000 (max layer: 48000*64)
    float* wdbuf  = ws + 9856000;          // 4160: Wd1 @0 (36), Wd2 @64 (2048), Wd3 @2112 (2048)

    const int nb = (GN + 255) / 256;   // 188
    const int KB = GN / 4;             // 12000 blocks, one wave per point
    const int EB = 3072;               // edge-kernel grid (grid-stride over points)

    pack_feats<<<nb, 256, 0, stream>>>(x, lat, lon, feats0);
    prep_wd<<<1, 256, 0, stream>>>(W1a, W2a, W3a, wdbuf);

    // layer 1: 3 -> (6,12,32)
    sq_kernel<3><<<nb, 256, 0, stream>>>(feats0, sqb);
    knn_wave3<<<KB, 256, 0, stream>>>(feats0, sqb, idx);
    p_kernel<3, 12><<<(GN * 12 + 255) / 256, 256, 0, stream>>>(feats0, W1a, pbuf);
    edge_l1<<<EB, 64, 0, stream>>>(feats0, pbuf, wdbuf, W1b, b1a, b1b, idx, h1);

    // layer 2: 32 -> (64,64,64)
    sq_kernel<32><<<nb, 256, 0, stream>>>(h1, sqb);
    knn_wave4<8><<<KB, 256, 0, stream>>>(h1, sqb, idx);
    p_kernel<32, 64><<<(GN * 64 + 255) / 256, 256, 0, stream>>>(h1, W2a, pbuf);
    edge_l2<<<EB, 64, 0, stream>>>(h1, pbuf, wdbuf + 64, W2b, b2a, b2b, idx, h2);

    // layer 3: 64 -> (128,32,8)
    sq_kernel<64><<<nb, 256, 0, stream>>>(h2, sqb);
    knn_wave4<16><<<KB, 256, 0, stream>>>(h2, sqb, idx);
    p_kernel<64, 32><<<(GN * 32 + 255) / 256, 256, 0, stream>>>(h2, W3a, pbuf);
    edge_l3<<<EB, 64, 0, stream>>>(h2, pbuf, wdbuf + 2112, W3b, b3a, b3b, idx, h3);

    // LSTM (only batch column 11 matters)
    lstm_pre<<<(4000 * 128 + 255) / 256, 256, 0, stream>>>(h3, Wih, bih, bhh, ut);
    lstm_seq<<<1, 64, 0, stream>>>(ut, Whh, outh);

    final_pred<<<(4000 + 255) / 256, 256, 0, stream>>>(outh, wth, ten, Wl, bl, (float*)d_out);
}

// Round 6
// 2702.569 us; speedup vs baseline: 1.5630x; 1.5322x over previous
//
#include <hip/hip_runtime.h>
#include <math.h>

#define GN 48000      // G*N = 96*500
#define NPTS 500
#define KNN 20

typedef float f2 __attribute__((ext_vector_type(2)));
typedef float f4 __attribute__((ext_vector_type(4)));

__device__ __forceinline__ float fsig(float x) {
    return __builtin_amdgcn_rcpf(1.0f + __expf(-x));
}

// feats = stack([x, lat, lon], -1) reshaped (G, N, 3)
__global__ void pack_feats(const float* __restrict__ x, const float* __restrict__ la,
                           const float* __restrict__ lo, float* __restrict__ o) {
    int t = blockIdx.x * 256 + threadIdx.x;
    if (t >= GN) return;
    o[t * 3 + 0] = x[t];
    o[t * 3 + 1] = la[t];
    o[t * 3 + 2] = lo[t];
}

template <int F>
__global__ void sq_kernel(const float* __restrict__ xin, float* __restrict__ sq) {
    int t = blockIdx.x * 256 + threadIdx.x;
    if (t >= GN) return;
    float s = 0.f;
#pragma unroll
    for (int f = 0; f < F; ++f) {
        float v = xin[(size_t)t * F + f];
        s = fmaf(v, v, s);
    }
    sq[t] = s;
}

// ---- wave-per-row kNN: lane l owns candidates j = l + 64m (m=0..7) ----
// Distances staged in LDS (bounds register demand -> no spill); selection:
// 20x { per-lane argmin over its 8 LDS slots (ascending j, strict <) ->
// 6-step shfl_xor butterfly argmin with (d,j) lexicographic tie-break ->
// lane 0 masks winner in LDS }. Matches jax.lax.top_k(-d) tie ordering.
// XCD swizzle: 12000 blocks % 8 == 0 -> bijective chunked remap.

__device__ __forceinline__ int swz_block(int bid) {
    return (bid & 7) * 1500 + (bid >> 3);   // 12000/8 = 1500
}

// F = 3 (scalar loads, tiny register footprint -> keep register-resident d)
__global__ void __launch_bounds__(256) knn_wave3(const float* __restrict__ xin,
                                                 const float* __restrict__ sq,
                                                 int* __restrict__ idx) {
    int wv = swz_block(blockIdx.x) * 4 + (threadIdx.x >> 6);   // point id
    int l = threadIdx.x & 63;
    int g = wv / NPTS, i = wv - g * NPTS;
    const float* base = xin + (size_t)g * NPTS * 3;
    const float* sqg = sq + g * NPTS;
    float x0 = base[i * 3], x1 = base[i * 3 + 1], x2 = base[i * 3 + 2];
    float sqi = sqg[i];
    float d[8];
#pragma unroll
    for (int m = 0; m < 8; ++m) {
        int j = l + 64 * m;
        if (j < NPTS) {
            float dot = x0 * base[j * 3];
            dot = fmaf(x1, base[j * 3 + 1], dot);
            dot = fmaf(x2, base[j * 3 + 2], dot);
            d[m] = sqi - 2.0f * dot + sqg[j];
        } else {
            d[m] = INFINITY;
        }
    }
    int myw = 0;
    for (int s = 0; s < KNN; ++s) {
        float bd = d[0]; int bj = l;
#pragma unroll
        for (int m = 1; m < 8; ++m) {
            bool take = d[m] < bd;
            bd = take ? d[m] : bd;
            bj = take ? (l + 64 * m) : bj;
        }
#pragma unroll
        for (int st = 1; st < 64; st <<= 1) {
            float od = __shfl_xor(bd, st, 64);
            int oj = __shfl_xor(bj, st, 64);
            bool take = (od < bd) || (od == bd && oj < bj);
            bd = take ? od : bd;
            bj = take ? oj : bj;
        }
        if (l == s) myw = bj;
        int r = bj - l;
#pragma unroll
        for (int m = 0; m < 8; ++m) if (r == 64 * m) d[m] = INFINITY;
    }
    if (l < KNN) idx[(size_t)wv * KNN + l] = myw;
}

// F = 4*F4 (float4 loads, 4-way split accumulation == prior passing kernel)
template <int F4>
__global__ void __launch_bounds__(256) knn_wave4(const float* __restrict__ xin,
                                                 const float* __restrict__ sq,
                                                 int* __restrict__ idx) {
    __shared__ float dls[4][512];
    int w = threadIdx.x >> 6;
    int wv = swz_block(blockIdx.x) * 4 + w;   // point id
    int l = threadIdx.x & 63;
    int g = wv / NPTS, i = wv - g * NPTS;
    const float4* base4 = (const float4*)(xin + (size_t)g * NPTS * (4 * F4));
    const float* sqg = sq + g * NPTS;
    float4 xi[F4];
#pragma unroll
    for (int ff = 0; ff < F4; ++ff) xi[ff] = base4[i * F4 + ff];
    float sqi = sqg[i];
    // distance phase: runtime loop, distances go straight to LDS
#pragma unroll 1
    for (int m = 0; m < 8; ++m) {
        int j = l + 64 * m;
        float dv = INFINITY;
        if (j < NPTS) {
            const float4* bj4 = base4 + j * F4;
            float a0 = 0.f, a1 = 0.f, a2 = 0.f, a3 = 0.f;
#pragma unroll
            for (int ff = 0; ff < F4; ++ff) {
                float4 v = bj4[ff];
                a0 = fmaf(xi[ff].x, v.x, a0);
                a1 = fmaf(xi[ff].y, v.y, a1);
                a2 = fmaf(xi[ff].z, v.z, a2);
                a3 = fmaf(xi[ff].w, v.w, a3);
            }
            float dot = (a0 + a1) + (a2 + a3);
            dv = sqi - 2.0f * dot + sqg[j];
        }
        dls[w][l + 64 * m] = dv;
    }
    __builtin_amdgcn_wave_barrier();
    // selection phase: 20 rounds of LDS argmin + butterfly
    int myw = 0;
#pragma unroll 1
    for (int s = 0; s < KNN; ++s) {
        float bd = INFINITY; int bj = 0;
#pragma unroll
        for (int m = 0; m < 8; ++m) {
            float dv = dls[w][l + 64 * m];
            bool take = dv < bd;          // ascending j, strict < -> earliest j on tie
            bd = take ? dv : bd;
            bj = take ? (l + 64 * m) : bj;
        }
#pragma unroll
        for (int st = 1; st < 64; st <<= 1) {
            float od = __shfl_xor(bd, st, 64);
            int oj = __shfl_xor(bj, st, 64);
            bool take = (od < bd) || (od == bd && oj < bj);
            bd = take ? od : bd;
            bj = take ? oj : bj;
        }
        if (l == s) myw = bj;
        __builtin_amdgcn_wave_barrier();
        if (l == 0) dls[w][bj] = INFINITY;   // bj uniform after butterfly
        __builtin_amdgcn_wave_barrier();
    }
    if (l < KNN) idx[(size_t)wv * KNN + l] = myw;
}

// Wd = Wa_top - Wa_bot for each layer (hid = xi*Wd + xj*Wa_bot + ba)
__global__ void prep_wd(const float* __restrict__ W1a, const float* __restrict__ W2a,
                        const float* __restrict__ W3a, float* __restrict__ wd) {
    int t = threadIdx.x;
    for (int i = t; i < 36; i += 256) {
        int f = i / 12, h = i - f * 12;
        wd[i] = W1a[f * 12 + h] - W1a[(3 + f) * 12 + h];
    }
    for (int i = t; i < 2048; i += 256) wd[64 + i] = W2a[i] - W2a[2048 + i];
    for (int i = t; i < 2048; i += 256) wd[2112 + i] = W3a[i] - W3a[2048 + i];
}

// p[s*H+h] = x[s] . Wa_bot[:, h]   (s = global point id)
template <int F, int H>
__global__ void p_kernel(const float* __restrict__ x, const float* __restrict__ Wa,
                         float* __restrict__ p) {
    int t = blockIdx.x * 256 + threadIdx.x;
    if (t >= GN * H) return;
    int s = t / H, hh = t - s * H;
    const float* xp = x + (size_t)s * F;
    float acc = 0.f;
#pragma unroll
    for (int f = 0; f < F; ++f) acc = fmaf(xp[f], Wa[(F + f) * H + hh], acc);
    p[t] = acc;
}

// ---- edge kernels: one wave per block, grid-stride over points, no barriers ----
// NOTE: idx holds graph-LOCAL neighbor indices; p gathers use per-graph base.

// layer 1: feat in 3, H=12, C=32
__global__ void __launch_bounds__(64) edge_l1(const float* __restrict__ x, const float* __restrict__ p,
        const float* __restrict__ wdg, const float* __restrict__ Wb, const float* __restrict__ ba,
        const float* __restrict__ bb, const int* __restrict__ idx, float* __restrict__ out) {
    __shared__ float sh[16];
    int l = threadIdx.x;
    int c = l & 31;
    int hl = (l < 12) ? l : 0;
    float wb[12];
#pragma unroll
    for (int h = 0; h < 12; ++h) wb[h] = Wb[h * 32 + c];
    float bbv = bb[c];
    float bav = ba[hl];
    float wd0 = wdg[0 * 12 + hl], wd1 = wdg[1 * 12 + hl], wd2 = wdg[2 * 12 + hl];
    for (int pt = blockIdx.x; pt < GN; pt += gridDim.x) {
        int g = pt / NPTS;
        const float* pg = p + (size_t)g * NPTS * 12;
        float x0 = x[pt * 3], x1 = x[pt * 3 + 1], x2 = x[pt * 3 + 2];
        float q = fmaf(x0, wd0, bav);
        q = fmaf(x1, wd1, q);
        q = fmaf(x2, wd2, q);
        const int4* ip4 = (const int4*)(idx + (size_t)pt * KNN);
        int jj[KNN];
#pragma unroll
        for (int b = 0; b < 5; ++b) {
            int4 v = ip4[b];
            jj[b * 4] = v.x; jj[b * 4 + 1] = v.y; jj[b * 4 + 2] = v.z; jj[b * 4 + 3] = v.w;
        }
        float acc = -INFINITY;
        float pj = pg[jj[0] * 12 + hl];
#pragma unroll
        for (int n = 0; n < KNN; ++n) {
            float pjn = (n < KNN - 1) ? pg[jj[n + 1] * 12 + hl] : 0.f;
            float hid = q + pj;
            hid = (hid >= 0.f) ? hid : 0.01f * hid;
            __builtin_amdgcn_wave_barrier();
            if (l < 12) sh[l] = hid;
            __builtin_amdgcn_wave_barrier();
            float4 h0 = ((float4*)sh)[0], h1v = ((float4*)sh)[1], h2v = ((float4*)sh)[2];
            __builtin_amdgcn_wave_barrier();
            float o = bbv;
            o = fmaf(h0.x, wb[0], o); o = fmaf(h0.y, wb[1], o);
            o = fmaf(h0.z, wb[2], o); o = fmaf(h0.w, wb[3], o);
            o = fmaf(h1v.x, wb[4], o); o = fmaf(h1v.y, wb[5], o);
            o = fmaf(h1v.z, wb[6], o); o = fmaf(h1v.w, wb[7], o);
            o = fmaf(h2v.x, wb[8], o); o = fmaf(h2v.y, wb[9], o);
            o = fmaf(h2v.z, wb[10], o); o = fmaf(h2v.w, wb[11], o);
            acc = fmaxf(acc, o);
            pj = pjn;
        }
        if (l < 32) out[(size_t)pt * 32 + c] = acc;
    }
}

// layer 2: feat in 32, H=64, C=64
__global__ void __launch_bounds__(64) edge_l2(const float* __restrict__ x, const float* __restrict__ p,
        const float* __restrict__ wdg, const float* __restrict__ Wb, const float* __restrict__ ba,
        const float* __restrict__ bb, const int* __restrict__ idx, float* __restrict__ out) {
    __shared__ float sh[64];
    int l = threadIdx.x;
    float wb[64];
#pragma unroll
    for (int h = 0; h < 64; ++h) wb[h] = Wb[h * 64 + l];
    float wd[32];
#pragma unroll
    for (int f = 0; f < 32; ++f) wd[f] = wdg[f * 64 + l];
    float bav = ba[l], bbv = bb[l];
    for (int pt = blockIdx.x; pt < GN; pt += gridDim.x) {
        int g = pt / NPTS;
        const float* pg = p + (size_t)g * NPTS * 64;
        const float4* xi4 = (const float4*)(x + (size_t)pt * 32);
        float q = bav;
#pragma unroll
        for (int ff = 0; ff < 8; ++ff) {
            float4 v = xi4[ff];
            q = fmaf(v.x, wd[ff * 4 + 0], q);
            q = fmaf(v.y, wd[ff * 4 + 1], q);
            q = fmaf(v.z, wd[ff * 4 + 2], q);
            q = fmaf(v.w, wd[ff * 4 + 3], q);
        }
        const int4* ip4 = (const int4*)(idx + (size_t)pt * KNN);
        int jj[KNN];
#pragma unroll
        for (int b = 0; b < 5; ++b) {
            int4 v = ip4[b];
            jj[b * 4] = v.x; jj[b * 4 + 1] = v.y; jj[b * 4 + 2] = v.z; jj[b * 4 + 3] = v.w;
        }
        float acc = -INFINITY;
        float pj = pg[jj[0] * 64 + l];
#pragma unroll
        for (int n = 0; n < KNN; ++n) {
            float pjn = (n < KNN - 1) ? pg[jj[n + 1] * 64 + l] : 0.f;
            float hid = q + pj;
            hid = (hid >= 0.f) ? hid : 0.01f * hid;
            __builtin_amdgcn_wave_barrier();
            sh[l] = hid;
            __builtin_amdgcn_wave_barrier();
            float o = bbv;
#pragma unroll
            for (int tt = 0; tt < 16; ++tt) {
                float4 hv = ((float4*)sh)[tt];
                o = fmaf(hv.x, wb[tt * 4 + 0], o);
                o = fmaf(hv.y, wb[tt * 4 + 1], o);
                o = fmaf(hv.z, wb[tt * 4 + 2], o);
                o = fmaf(hv.w, wb[tt * 4 + 3], o);
            }
            __builtin_amdgcn_wave_barrier();
            acc = fmaxf(acc, o);
            pj = pjn;
        }
        out[(size_t)pt * 64 + l] = acc;
    }
}

// layer 3: feat in 64, H=32, C=8
__global__ void __launch_bounds__(64) edge_l3(const float* __restrict__ x, const float* __restrict__ p,
        const float* __restrict__ wdg, const float* __restrict__ Wb, const float* __restrict__ ba,
        const float* __restrict__ bb, const int* __restrict__ idx, float* __restrict__ out) {
    __shared__ float sh[32];
    int l = threadIdx.x;
    int hh = l & 31, fh = l >> 5;    // hidden idx, f-half
    int c = l & 7, hseg = l >> 3;    // out channel, h-segment (0..7)
    float wd[32];
#pragma unroll
    for (int f2_ = 0; f2_ < 32; ++f2_) wd[f2_] = wdg[(fh * 32 + f2_) * 32 + hh];
    float wb[4];
#pragma unroll
    for (int e = 0; e < 4; ++e) wb[e] = Wb[(hseg * 4 + e) * 8 + c];
    float bav = ba[hh], bbv = bb[c];
    for (int pt = blockIdx.x; pt < GN; pt += gridDim.x) {
        int g = pt / NPTS;
        const float* pg = p + (size_t)g * NPTS * 32;
        const float4* xi4 = (const float4*)(x + (size_t)pt * 64);
        float qp = 0.f;
#pragma unroll
        for (int ff = 0; ff < 8; ++ff) {
            float4 v = xi4[fh * 8 + ff];
            qp = fmaf(v.x, wd[ff * 4 + 0], qp);
            qp = fmaf(v.y, wd[ff * 4 + 1], qp);
            qp = fmaf(v.z, wd[ff * 4 + 2], qp);
            qp = fmaf(v.w, wd[ff * 4 + 3], qp);
        }
        float q = bav + qp + __shfl_xor(qp, 32, 64);
        const int4* ip4 = (const int4*)(idx + (size_t)pt * KNN);
        int jj[KNN];
#pragma unroll
        for (int b = 0; b < 5; ++b) {
            int4 v = ip4[b];
            jj[b * 4] = v.x; jj[b * 4 + 1] = v.y; jj[b * 4 + 2] = v.z; jj[b * 4 + 3] = v.w;
        }
        float acc = -INFINITY;
        float pj = pg[jj[0] * 32 + hh];
#pragma unroll
        for (int n = 0; n < KNN; ++n) {
            float pjn = (n < KNN - 1) ? pg[jj[n + 1] * 32 + hh] : 0.f;
            float hid = q + pj;
            hid = (hid >= 0.f) ? hid : 0.01f * hid;
            __builtin_amdgcn_wave_barrier();
            if (l < 32) sh[l] = hid;
            __builtin_amdgcn_wave_barrier();
            float4 hv = ((float4*)sh)[hseg];
            __builtin_amdgcn_wave_barrier();
            float o = hv.x * wb[0];
            o = fmaf(hv.y, wb[1], o);
            o = fmaf(hv.z, wb[2], o);
            o = fmaf(hv.w, wb[3], o);
            o += __shfl_xor(o, 8, 64);
            o += __shfl_xor(o, 16, 64);
            o += __shfl_xor(o, 32, 64);
            acc = fmaxf(acc, o + bbv);
            pj = pjn;
        }
        if (l < 8) out[(size_t)pt * 8 + c] = acc;
    }
}

// ut[j][s] = bih[j] + bhh[j] + seq[s] . Wih[j,:]   (transposed: per-gate contiguous in s)
__global__ void lstm_pre(const float* __restrict__ h3, const float* __restrict__ Wih,
                         const float* __restrict__ bih, const float* __restrict__ bhh,
                         float* __restrict__ ut) {
    int t = blockIdx.x * 256 + threadIdx.x;
    if (t >= 4000 * 128) return;
    int j = t / 4000, s = t - j * 4000;
    int b = s / 500, n = s - b * 500;
    const float* xp = h3 + ((size_t)(b * 12 + 11) * 500 + n) * 8;
    float acc = bih[j] + bhh[j];
#pragma unroll
    for (int f = 0; f < 8; ++f) acc = fmaf(xp[f], Wih[j * 8 + f], acc);
    ut[(size_t)j * 4000 + s] = acc;
}

// single-wave barrier-free LSTM; lane l owns gates l and l+64.
__global__ void __launch_bounds__(64) lstm_seq(const float* __restrict__ ut,
                                               const float* __restrict__ Whh,
                                               float* __restrict__ outh_t) {
    __shared__ float sh[64];
    int l = threadIdx.x;
    f2 w0[16], w1[16];
#pragma unroll
    for (int k = 0; k < 16; ++k) {
        w0[k] = f2{Whh[l * 32 + 2 * k], Whh[l * 32 + 2 * k + 1]};
        w1[k] = f2{Whh[(l + 64) * 32 + 2 * k], Whh[(l + 64) * 32 + 2 * k + 1]};
    }
    bool lo = (l < 32);
    float m2 = lo ? 2.0f : 1.0f;     // tanh-from-sigmoid fixup: lane<32 needs tanh(g1)
    float a2 = lo ? -1.0f : 0.0f;
    float c = 0.f;
    sh[l] = 0.f;                     // h = 0
    const float* u0p = ut + (size_t)l * 4000;
    const float* u1p = ut + (size_t)(l + 64) * 4000;
    f4 ua = *(const f4*)(u0p);
    f4 ub = *(const f4*)(u1p);
    f4 na = ua, nb = ub;
    const f2* shv = (const f2*)sh;

#define LSTM_STEP(U0, U1, HOUT) {                                       \
        f2 acc0 = f2{(U0), 0.f}, acc1 = f2{(U1), 0.f};                  \
        _Pragma("unroll")                                               \
        for (int k = 0; k < 16; ++k) {                                  \
            f2 hp = shv[k];                                             \
            acc0 = __builtin_elementwise_fma(w0[k], hp, acc0);          \
            acc1 = __builtin_elementwise_fma(w1[k], hp, acc1);          \
        }                                                               \
        float g0 = acc0.x + acc0.y, g1 = acc1.x + acc1.y;               \
        float s0 = fsig(g0);                                            \
        float t1 = fmaf(fsig(m2 * g1), m2, a2);                         \
        float part = s0 * t1;                                           \
        float sf = __shfl_xor(s0, 32, 64);                              \
        float so = __shfl_xor(t1, 32, 64);                              \
        c = fmaf(sf, c, part);                                          \
        float tc = fmaf(fsig(c + c), 2.f, -1.f);                        \
        float h = so * tc;                                              \
        __builtin_amdgcn_wave_barrier();                                \
        sh[l] = h;                                                      \
        __builtin_amdgcn_wave_barrier();                                \
        HOUT = h;                                                       \
    }

    for (int s4 = 0; s4 < 4000; s4 += 4) {
        if (s4 + 4 < 4000) {
            na = *(const f4*)(u0p + s4 + 4);
            nb = *(const f4*)(u1p + s4 + 4);
        }
        f4 hq;
        LSTM_STEP(ua.x, ub.x, hq.x);
        LSTM_STEP(ua.y, ub.y, hq.y);
        LSTM_STEP(ua.z, ub.z, hq.z);
        LSTM_STEP(ua.w, ub.w, hq.w);
        if (lo) *(f4*)(outh_t + (size_t)l * 4000 + s4) = hq;
        ua = na; ub = nb;
    }
#undef LSTM_STEP
}

// emb = [out(32), weather[s%8, 11, :](8), time_enc[s%8, 11, :](8)] @ Wl + bl
__global__ void final_pred(const float* __restrict__ outh_t, const float* __restrict__ wth,
                           const float* __restrict__ ten, const float* __restrict__ Wl,
                           const float* __restrict__ bl, float* __restrict__ pred) {
    int s = blockIdx.x * 256 + threadIdx.x;
    if (s >= 4000) return;
    float a = bl[0];
#pragma unroll
    for (int k = 0; k < 32; ++k) a = fmaf(outh_t[(size_t)k * 4000 + s], Wl[k], a);
    int r = s & 7;   // s % 8, replicating jnp.tile row indexing
#pragma unroll
    for (int k = 0; k < 8; ++k) a = fmaf(wth[(r * 12 + 11) * 8 + k], Wl[32 + k], a);
#pragma unroll
    for (int k = 0; k < 8; ++k) a = fmaf(ten[(r * 12 + 11) * 8 + k], Wl[40 + k], a);
    pred[s] = a;
}

extern "C" void kernel_launch(void* const* d_in, const int* in_sizes, int n_in,
                              void* d_out, int out_size, void* d_ws, size_t ws_size,
                              hipStream_t stream) {
    const float* x   = (const float*)d_in[0];
    const float* lat = (const float*)d_in[1];
    const float* lon = (const float*)d_in[2];
    const float* wth = (const float*)d_in[3];
    const float* ten = (const float*)d_in[4];
    const float* W1a = (const float*)d_in[5];
    const float* b1a = (const float*)d_in[6];
    const float* W1b = (const float*)d_in[7];
    const float* b1b = (const float*)d_in[8];
    const float* W2a = (const float*)d_in[9];
    const float* b2a = (const float*)d_in[10];
    const float* W2b = (const float*)d_in[11];
    const float* b2b = (const float*)d_in[12];
    const float* W3a = (const float*)d_in[13];
    const float* b3a = (const float*)d_in[14];
    const float* W3b = (const float*)d_in[15];
    const float* b3b = (const float*)d_in[16];
    const float* Wih = (const float*)d_in[17];
    const float* Whh = (const float*)d_in[18];
    const float* bih = (const float*)d_in[19];
    const float* bhh = (const float*)d_in[20];
    const float* Wl  = (const float*)d_in[21];
    const float* bl  = (const float*)d_in[22];

    float* ws = (float*)d_ws;
    float* feats0 = ws;                    // 144000
    float* h1     = ws + 144000;           // 1536000
    float* h2     = ws + 1680000;          // 3072000
    float* h3     = ws + 4752000;          // 384000
    float* sqb    = ws + 5136000;          // 48000
    float* ut     = ws + 5184000;          // 512000 (transposed u: [128][4000])
    float* outh   = ws + 5696000;          // 128000 (transposed: [32][4000])
    int*   idx    = (int*)(ws + 5824000);  // 960000 ints
    float* pbuf   = ws + 6784000;          // 3072000 (max layer: 48000*64)
    float* wdbuf  = ws + 9856000;          // 4160: Wd1 @0 (36), Wd2 @64 (2048), Wd3 @2112 (2048)

    const int nb = (GN + 255) / 256;   // 188
    const int KB = GN / 4;             // 12000 blocks, one wave per point
    const int EB = 3072;               // edge-kernel grid (grid-stride over points)

    pack_feats<<<nb, 256, 0, stream>>>(x, lat, lon, feats0);
    prep_wd<<<1, 256, 0, stream>>>(W1a, W2a, W3a, wdbuf);

    // layer 1: 3 -> (6,12,32)
    sq_kernel<3><<<nb, 256, 0, stream>>>(feats0, sqb);
    knn_wave3<<<KB, 256, 0, stream>>>(feats0, sqb, idx);
    p_kernel<3, 12><<<(GN * 12 + 255) / 256, 256, 0, stream>>>(feats0, W1a, pbuf);
    edge_l1<<<EB, 64, 0, stream>>>(feats0, pbuf, wdbuf, W1b, b1a, b1b, idx, h1);

    // layer 2: 32 -> (64,64,64)
    sq_kernel<32><<<nb, 256, 0, stream>>>(h1, sqb);
    knn_wave4<8><<<KB, 256, 0, stream>>>(h1, sqb, idx);
    p_kernel<32, 64><<<(GN * 64 + 255) / 256, 256, 0, stream>>>(h1, W2a, pbuf);
    edge_l2<<<EB, 64, 0, stream>>>(h1, pbuf, wdbuf + 64, W2b, b2a, b2b, idx, h2);

    // layer 3: 64 -> (128,32,8)
    sq_kernel<64><<<nb, 256, 0, stream>>>(h2, sqb);
    knn_wave4<16><<<KB, 256, 0, stream>>>(h2, sqb, idx);
    p_kernel<64, 32><<<(GN * 32 + 255) / 256, 256, 0, stream>>>(h2, W3a, pbuf);
    edge_l3<<<EB, 64, 0, stream>>>(h2, pbuf, wdbuf + 2112, W3b, b3a, b3b, idx, h3);

    // LSTM (only batch column 11 matters)
    lstm_pre<<<(4000 * 128 + 255) / 256, 256, 0, stream>>>(h3, Wih, bih, bhh, ut);
    lstm_seq<<<1, 64, 0, stream>>>(ut, Whh, outh);

    final_pred<<<(4000 + 255) / 256, 256, 0, stream>>>(outh, wth, ten, Wl, bl, (float*)d_out);
}

// Round 7
// 1351.966 us; speedup vs baseline: 3.1244x; 1.9990x over previous
//
#include <hip/hip_runtime.h>
#include <math.h>

#define GN2 4000      // points that matter: 8 graphs (b*12+11) x 500
#define NPTS 500
#define KNN 20

typedef float f2 __attribute__((ext_vector_type(2)));
typedef float f4 __attribute__((ext_vector_type(4)));

__device__ __forceinline__ float fsig(float x) {
    return __builtin_amdgcn_rcpf(1.0f + __expf(-x));
}

// Only graphs g = b*12+11 feed the output. Gather their features compactly:
// compact point s = b*500+n  <-  source (b*12+11)*500+n
__global__ void pack_feats(const float* __restrict__ x, const float* __restrict__ la,
                           const float* __restrict__ lo, float* __restrict__ o) {
    int s = blockIdx.x * 256 + threadIdx.x;
    if (s >= GN2) return;
    int b = s / NPTS, n = s - b * NPTS;
    int src = (b * 12 + 11) * NPTS + n;
    o[s * 3 + 0] = x[src];
    o[s * 3 + 1] = la[src];
    o[s * 3 + 2] = lo[src];
}

template <int F>
__global__ void sq_kernel(const float* __restrict__ xin, float* __restrict__ sq) {
    int t = blockIdx.x * 256 + threadIdx.x;
    if (t >= GN2) return;
    float s = 0.f;
#pragma unroll
    for (int f = 0; f < F; ++f) {
        float v = xin[(size_t)t * F + f];
        s = fmaf(v, v, s);
    }
    sq[t] = s;
}

// ---- wave-per-row kNN (identical arithmetic to passing round-6 kernels) ----
// 1000 blocks % 8 == 0 -> bijective chunked XCD remap, cpx = 125.
__device__ __forceinline__ int swz_block(int bid) {
    return (bid & 7) * 125 + (bid >> 3);
}

// F = 3 (scalar loads, register-resident d)
__global__ void __launch_bounds__(256) knn_wave3(const float* __restrict__ xin,
                                                 const float* __restrict__ sq,
                                                 int* __restrict__ idx) {
    int wv = swz_block(blockIdx.x) * 4 + (threadIdx.x >> 6);   // point id
    int l = threadIdx.x & 63;
    int g = wv / NPTS, i = wv - g * NPTS;
    const float* base = xin + (size_t)g * NPTS * 3;
    const float* sqg = sq + g * NPTS;
    float x0 = base[i * 3], x1 = base[i * 3 + 1], x2 = base[i * 3 + 2];
    float sqi = sqg[i];
    float d[8];
#pragma unroll
    for (int m = 0; m < 8; ++m) {
        int j = l + 64 * m;
        if (j < NPTS) {
            float dot = x0 * base[j * 3];
            dot = fmaf(x1, base[j * 3 + 1], dot);
            dot = fmaf(x2, base[j * 3 + 2], dot);
            d[m] = sqi - 2.0f * dot + sqg[j];
        } else {
            d[m] = INFINITY;
        }
    }
    int myw = 0;
    for (int s = 0; s < KNN; ++s) {
        float bd = d[0]; int bj = l;
#pragma unroll
        for (int m = 1; m < 8; ++m) {
            bool take = d[m] < bd;
            bd = take ? d[m] : bd;
            bj = take ? (l + 64 * m) : bj;
        }
#pragma unroll
        for (int st = 1; st < 64; st <<= 1) {
            float od = __shfl_xor(bd, st, 64);
            int oj = __shfl_xor(bj, st, 64);
            bool take = (od < bd) || (od == bd && oj < bj);
            bd = take ? od : bd;
            bj = take ? oj : bj;
        }
        if (l == s) myw = bj;
        int r = bj - l;
#pragma unroll
        for (int m = 0; m < 8; ++m) if (r == 64 * m) d[m] = INFINITY;
    }
    if (l < KNN) idx[(size_t)wv * KNN + l] = myw;
}

// F = 4*F4: distances staged in LDS (bounds register demand -> no spill)
template <int F4>
__global__ void __launch_bounds__(256) knn_wave4(const float* __restrict__ xin,
                                                 const float* __restrict__ sq,
                                                 int* __restrict__ idx) {
    __shared__ float dls[4][512];
    int w = threadIdx.x >> 6;
    int wv = swz_block(blockIdx.x) * 4 + w;   // point id
    int l = threadIdx.x & 63;
    int g = wv / NPTS, i = wv - g * NPTS;
    const float4* base4 = (const float4*)(xin + (size_t)g * NPTS * (4 * F4));
    const float* sqg = sq + g * NPTS;
    float4 xi[F4];
#pragma unroll
    for (int ff = 0; ff < F4; ++ff) xi[ff] = base4[i * F4 + ff];
    float sqi = sqg[i];
#pragma unroll 1
    for (int m = 0; m < 8; ++m) {
        int j = l + 64 * m;
        float dv = INFINITY;
        if (j < NPTS) {
            const float4* bj4 = base4 + j * F4;
            float a0 = 0.f, a1 = 0.f, a2 = 0.f, a3 = 0.f;
#pragma unroll
            for (int ff = 0; ff < F4; ++ff) {
                float4 v = bj4[ff];
                a0 = fmaf(xi[ff].x, v.x, a0);
                a1 = fmaf(xi[ff].y, v.y, a1);
                a2 = fmaf(xi[ff].z, v.z, a2);
                a3 = fmaf(xi[ff].w, v.w, a3);
            }
            float dot = (a0 + a1) + (a2 + a3);
            dv = sqi - 2.0f * dot + sqg[j];
        }
        dls[w][l + 64 * m] = dv;
    }
    __builtin_amdgcn_wave_barrier();
    int myw = 0;
#pragma unroll 1
    for (int s = 0; s < KNN; ++s) {
        float bd = INFINITY; int bj = 0;
#pragma unroll
        for (int m = 0; m < 8; ++m) {
            float dv = dls[w][l + 64 * m];
            bool take = dv < bd;          // ascending j, strict < -> earliest j on tie
            bd = take ? dv : bd;
            bj = take ? (l + 64 * m) : bj;
        }
#pragma unroll
        for (int st = 1; st < 64; st <<= 1) {
            float od = __shfl_xor(bd, st, 64);
            int oj = __shfl_xor(bj, st, 64);
            bool take = (od < bd) || (od == bd && oj < bj);
            bd = take ? od : bd;
            bj = take ? oj : bj;
        }
        if (l == s) myw = bj;
        __builtin_amdgcn_wave_barrier();
        if (l == 0) dls[w][bj] = INFINITY;   // bj uniform after butterfly
        __builtin_amdgcn_wave_barrier();
    }
    if (l < KNN) idx[(size_t)wv * KNN + l] = myw;
}

// Wd = Wa_top - Wa_bot for each layer (hid = xi*Wd + xj*Wa_bot + ba)
__global__ void prep_wd(const float* __restrict__ W1a, const float* __restrict__ W2a,
                        const float* __restrict__ W3a, float* __restrict__ wd) {
    int t = threadIdx.x;
    for (int i = t; i < 36; i += 256) {
        int f = i / 12, h = i - f * 12;
        wd[i] = W1a[f * 12 + h] - W1a[(3 + f) * 12 + h];
    }
    for (int i = t; i < 2048; i += 256) wd[64 + i] = W2a[i] - W2a[2048 + i];
    for (int i = t; i < 2048; i += 256) wd[2112 + i] = W3a[i] - W3a[2048 + i];
}

// p[s*H+h] = x[s] . Wa_bot[:, h]   (s = compact point id)
template <int F, int H>
__global__ void p_kernel(const float* __restrict__ x, const float* __restrict__ Wa,
                         float* __restrict__ p) {
    int t = blockIdx.x * 256 + threadIdx.x;
    if (t >= GN2 * H) return;
    int s = t / H, hh = t - s * H;
    const float* xp = x + (size_t)s * F;
    float acc = 0.f;
#pragma unroll
    for (int f = 0; f < F; ++f) acc = fmaf(xp[f], Wa[(F + f) * H + hh], acc);
    p[t] = acc;
}

// ---- edge kernels: one wave per block, grid-stride over points, no barriers ----

// layer 1: feat in 3, H=12, C=32
__global__ void __launch_bounds__(64) edge_l1(const float* __restrict__ x, const float* __restrict__ p,
        const float* __restrict__ wdg, const float* __restrict__ Wb, const float* __restrict__ ba,
        const float* __restrict__ bb, const int* __restrict__ idx, float* __restrict__ out) {
    __shared__ float sh[16];
    int l = threadIdx.x;
    int c = l & 31;
    int hl = (l < 12) ? l : 0;
    float wb[12];
#pragma unroll
    for (int h = 0; h < 12; ++h) wb[h] = Wb[h * 32 + c];
    float bbv = bb[c];
    float bav = ba[hl];
    float wd0 = wdg[0 * 12 + hl], wd1 = wdg[1 * 12 + hl], wd2 = wdg[2 * 12 + hl];
    for (int pt = blockIdx.x; pt < GN2; pt += gridDim.x) {
        int g = pt / NPTS;
        const float* pg = p + (size_t)g * NPTS * 12;
        float x0 = x[pt * 3], x1 = x[pt * 3 + 1], x2 = x[pt * 3 + 2];
        float q = fmaf(x0, wd0, bav);
        q = fmaf(x1, wd1, q);
        q = fmaf(x2, wd2, q);
        const int4* ip4 = (const int4*)(idx + (size_t)pt * KNN);
        int jj[KNN];
#pragma unroll
        for (int b = 0; b < 5; ++b) {
            int4 v = ip4[b];
            jj[b * 4] = v.x; jj[b * 4 + 1] = v.y; jj[b * 4 + 2] = v.z; jj[b * 4 + 3] = v.w;
        }
        float acc = -INFINITY;
        float pj = pg[jj[0] * 12 + hl];
#pragma unroll
        for (int n = 0; n < KNN; ++n) {
            float pjn = (n < KNN - 1) ? pg[jj[n + 1] * 12 + hl] : 0.f;
            float hid = q + pj;
            hid = (hid >= 0.f) ? hid : 0.01f * hid;
            __builtin_amdgcn_wave_barrier();
            if (l < 12) sh[l] = hid;
            __builtin_amdgcn_wave_barrier();
            float4 h0 = ((float4*)sh)[0], h1v = ((float4*)sh)[1], h2v = ((float4*)sh)[2];
            __builtin_amdgcn_wave_barrier();
            float o = bbv;
            o = fmaf(h0.x, wb[0], o); o = fmaf(h0.y, wb[1], o);
            o = fmaf(h0.z, wb[2], o); o = fmaf(h0.w, wb[3], o);
            o = fmaf(h1v.x, wb[4], o); o = fmaf(h1v.y, wb[5], o);
            o = fmaf(h1v.z, wb[6], o); o = fmaf(h1v.w, wb[7], o);
            o = fmaf(h2v.x, wb[8], o); o = fmaf(h2v.y, wb[9], o);
            o = fmaf(h2v.z, wb[10], o); o = fmaf(h2v.w, wb[11], o);
            acc = fmaxf(acc, o);
            pj = pjn;
        }
        if (l < 32) out[(size_t)pt * 32 + c] = acc;
    }
}

// layer 2: feat in 32, H=64, C=64
__global__ void __launch_bounds__(64) edge_l2(const float* __restrict__ x, const float* __restrict__ p,
        const float* __restrict__ wdg, const float* __restrict__ Wb, const float* __restrict__ ba,
        const float* __restrict__ bb, const int* __restrict__ idx, float* __restrict__ out) {
    __shared__ float sh[64];
    int l = threadIdx.x;
    float wb[64];
#pragma unroll
    for (int h = 0; h < 64; ++h) wb[h] = Wb[h * 64 + l];
    float wd[32];
#pragma unroll
    for (int f = 0; f < 32; ++f) wd[f] = wdg[f * 64 + l];
    float bav = ba[l], bbv = bb[l];
    for (int pt = blockIdx.x; pt < GN2; pt += gridDim.x) {
        int g = pt / NPTS;
        const float* pg = p + (size_t)g * NPTS * 64;
        const float4* xi4 = (const float4*)(x + (size_t)pt * 32);
        float q = bav;
#pragma unroll
        for (int ff = 0; ff < 8; ++ff) {
            float4 v = xi4[ff];
            q = fmaf(v.x, wd[ff * 4 + 0], q);
            q = fmaf(v.y, wd[ff * 4 + 1], q);
            q = fmaf(v.z, wd[ff * 4 + 2], q);
            q = fmaf(v.w, wd[ff * 4 + 3], q);
        }
        const int4* ip4 = (const int4*)(idx + (size_t)pt * KNN);
        int jj[KNN];
#pragma unroll
        for (int b = 0; b < 5; ++b) {
            int4 v = ip4[b];
            jj[b * 4] = v.x; jj[b * 4 + 1] = v.y; jj[b * 4 + 2] = v.z; jj[b * 4 + 3] = v.w;
        }
        float acc = -INFINITY;
        float pj = pg[jj[0] * 64 + l];
#pragma unroll
        for (int n = 0; n < KNN; ++n) {
            float pjn = (n < KNN - 1) ? pg[jj[n + 1] * 64 + l] : 0.f;
            float hid = q + pj;
            hid = (hid >= 0.f) ? hid : 0.01f * hid;
            __builtin_amdgcn_wave_barrier();
            sh[l] = hid;
            __builtin_amdgcn_wave_barrier();
            float o = bbv;
#pragma unroll
            for (int tt = 0; tt < 16; ++tt) {
                float4 hv = ((float4*)sh)[tt];
                o = fmaf(hv.x, wb[tt * 4 + 0], o);
                o = fmaf(hv.y, wb[tt * 4 + 1], o);
                o = fmaf(hv.z, wb[tt * 4 + 2], o);
                o = fmaf(hv.w, wb[tt * 4 + 3], o);
            }
            __builtin_amdgcn_wave_barrier();
            acc = fmaxf(acc, o);
            pj = pjn;
        }
        out[(size_t)pt * 64 + l] = acc;
    }
}

// layer 3: feat in 64, H=32, C=8
__global__ void __launch_bounds__(64) edge_l3(const float* __restrict__ x, const float* __restrict__ p,
        const float* __restrict__ wdg, const float* __restrict__ Wb, const float* __restrict__ ba,
        const float* __restrict__ bb, const int* __restrict__ idx, float* __restrict__ out) {
    __shared__ float sh[32];
    int l = threadIdx.x;
    int hh = l & 31, fh = l >> 5;    // hidden idx, f-half
    int c = l & 7, hseg = l >> 3;    // out channel, h-segment (0..7)
    float wd[32];
#pragma unroll
    for (int f2_ = 0; f2_ < 32; ++f2_) wd[f2_] = wdg[(fh * 32 + f2_) * 32 + hh];
    float wb[4];
#pragma unroll
    for (int e = 0; e < 4; ++e) wb[e] = Wb[(hseg * 4 + e) * 8 + c];
    float bav = ba[hh], bbv = bb[c];
    for (int pt = blockIdx.x; pt < GN2; pt += gridDim.x) {
        int g = pt / NPTS;
        const float* pg = p + (size_t)g * NPTS * 32;
        const float4* xi4 = (const float4*)(x + (size_t)pt * 64);
        float qp = 0.f;
#pragma unroll
        for (int ff = 0; ff < 8; ++ff) {
            float4 v = xi4[fh * 8 + ff];
            qp = fmaf(v.x, wd[ff * 4 + 0], qp);
            qp = fmaf(v.y, wd[ff * 4 + 1], qp);
            qp = fmaf(v.z, wd[ff * 4 + 2], qp);
            qp = fmaf(v.w, wd[ff * 4 + 3], qp);
        }
        float q = bav + qp + __shfl_xor(qp, 32, 64);
        const int4* ip4 = (const int4*)(idx + (size_t)pt * KNN);
        int jj[KNN];
#pragma unroll
        for (int b = 0; b < 5; ++b) {
            int4 v = ip4[b];
            jj[b * 4] = v.x; jj[b * 4 + 1] = v.y; jj[b * 4 + 2] = v.z; jj[b * 4 + 3] = v.w;
        }
        float acc = -INFINITY;
        float pj = pg[jj[0] * 32 + hh];
#pragma unroll
        for (int n = 0; n < KNN; ++n) {
            float pjn = (n < KNN - 1) ? pg[jj[n + 1] * 32 + hh] : 0.f;
            float hid = q + pj;
            hid = (hid >= 0.f) ? hid : 0.01f * hid;
            __builtin_amdgcn_wave_barrier();
            if (l < 32) sh[l] = hid;
            __builtin_amdgcn_wave_barrier();
            float4 hv = ((float4*)sh)[hseg];
            __builtin_amdgcn_wave_barrier();
            float o = hv.x * wb[0];
            o = fmaf(hv.y, wb[1], o);
            o = fmaf(hv.z, wb[2], o);
            o = fmaf(hv.w, wb[3], o);
            o += __shfl_xor(o, 8, 64);
            o += __shfl_xor(o, 16, 64);
            o += __shfl_xor(o, 32, 64);
            acc = fmaxf(acc, o + bbv);
            pj = pjn;
        }
        if (l < 8) out[(size_t)pt * 8 + c] = acc;
    }
}

// ut[j][s] = bih[j] + bhh[j] + h3[s] . Wih[j,:]   (h3 compact: [s][8])
__global__ void lstm_pre(const float* __restrict__ h3, const float* __restrict__ Wih,
                         const float* __restrict__ bih, const float* __restrict__ bhh,
                         float* __restrict__ ut) {
    int t = blockIdx.x * 256 + threadIdx.x;
    if (t >= 4000 * 128) return;
    int j = t / 4000, s = t - j * 4000;
    const float* xp = h3 + (size_t)s * 8;
    float acc = bih[j] + bhh[j];
#pragma unroll
    for (int f = 0; f < 8; ++f) acc = fmaf(xp[f], Wih[j * 8 + f], acc);
    ut[(size_t)j * 4000 + s] = acc;
}

// single-wave barrier-free LSTM; lane l owns gates l and l+64.
// h broadcast via LDS (8x ds_read_b128); matvec split into 2x 4-deep f4 chains
// per gate (latency ~4x lower than one 16-deep packed chain).
__global__ void __launch_bounds__(64) lstm_seq(const float* __restrict__ ut,
                                               const float* __restrict__ Whh,
                                               float* __restrict__ outh_t) {
    __shared__ float sh[64];
    int l = threadIdx.x;
    f4 w0[8], w1[8];
#pragma unroll
    for (int k = 0; k < 8; ++k) {
        w0[k] = *(const f4*)(Whh + l * 32 + 4 * k);
        w1[k] = *(const f4*)(Whh + (l + 64) * 32 + 4 * k);
    }
    bool lo = (l < 32);
    float m2 = lo ? 2.0f : 1.0f;     // tanh-from-sigmoid fixup: lane<32 needs tanh(g1)
    float a2 = lo ? -1.0f : 0.0f;
    float c = 0.f;
    sh[l] = 0.f;                     // h = 0
    const float* u0p = ut + (size_t)l * 4000;
    const float* u1p = ut + (size_t)(l + 64) * 4000;
    f4 ua = *(const f4*)(u0p);
    f4 ub = *(const f4*)(u1p);
    f4 na = ua, nb = ub;
    const f4* shv = (const f4*)sh;

#define LSTM_STEP(U0, U1, HOUT) {                                       \
        f4 h0_ = shv[0], h1_ = shv[1], h2_ = shv[2], h3_ = shv[3];      \
        f4 h4_ = shv[4], h5_ = shv[5], h6_ = shv[6], h7_ = shv[7];      \
        f4 a0 = w0[0] * h0_,  b0 = w0[1] * h1_;                         \
        f4 a1 = w1[0] * h0_,  b1 = w1[1] * h1_;                         \
        a0 = __builtin_elementwise_fma(w0[2], h2_, a0);                 \
        b0 = __builtin_elementwise_fma(w0[3], h3_, b0);                 \
        a1 = __builtin_elementwise_fma(w1[2], h2_, a1);                 \
        b1 = __builtin_elementwise_fma(w1[3], h3_, b1);                 \
        a0 = __builtin_elementwise_fma(w0[4], h4_, a0);                 \
        b0 = __builtin_elementwise_fma(w0[5], h5_, b0);                 \
        a1 = __builtin_elementwise_fma(w1[4], h4_, a1);                 \
        b1 = __builtin_elementwise_fma(w1[5], h5_, b1);                 \
        a0 = __builtin_elementwise_fma(w0[6], h6_, a0);                 \
        b0 = __builtin_elementwise_fma(w0[7], h7_, b0);                 \
        a1 = __builtin_elementwise_fma(w1[6], h6_, a1);                 \
        b1 = __builtin_elementwise_fma(w1[7], h7_, b1);                 \
        f4 s0v = a0 + b0, s1v = a1 + b1;                                \
        float g0 = U0 + ((s0v.x + s0v.y) + (s0v.z + s0v.w));            \
        float g1 = U1 + ((s1v.x + s1v.y) + (s1v.z + s1v.w));            \
        float s0 = fsig(g0);                                            \
        float t1 = fmaf(fsig(m2 * g1), m2, a2);                         \
        float part = s0 * t1;                                           \
        float sf = __shfl_xor(s0, 32, 64);                              \
        float so = __shfl_xor(t1, 32, 64);                              \
        c = fmaf(sf, c, part);                                          \
        float tc = fmaf(fsig(c + c), 2.f, -1.f);                        \
        float h = so * tc;                                              \
        __builtin_amdgcn_wave_barrier();                                \
        sh[l] = h;                                                      \
        __builtin_amdgcn_wave_barrier();                                \
        HOUT = h;                                                       \
    }

    for (int s4 = 0; s4 < 4000; s4 += 4) {
        if (s4 + 4 < 4000) {
            na = *(const f4*)(u0p + s4 + 4);
            nb = *(const f4*)(u1p + s4 + 4);
        }
        f4 hq;
        LSTM_STEP(ua.x, ub.x, hq.x);
        LSTM_STEP(ua.y, ub.y, hq.y);
        LSTM_STEP(ua.z, ub.z, hq.z);
        LSTM_STEP(ua.w, ub.w, hq.w);
        if (lo) *(f4*)(outh_t + (size_t)l * 4000 + s4) = hq;
        ua = na; ub = nb;
    }
#undef LSTM_STEP
}

// emb = [out(32), weather[s%8, 11, :](8), time_enc[s%8, 11, :](8)] @ Wl + bl
__global__ void final_pred(const float* __restrict__ outh_t, const float* __restrict__ wth,
                           const float* __restrict__ ten, const float* __restrict__ Wl,
                           const float* __restrict__ bl, float* __restrict__ pred) {
    int s = blockIdx.x * 256 + threadIdx.x;
    if (s >= 4000) return;
    float a = bl[0];
#pragma unroll
    for (int k = 0; k < 32; ++k) a = fmaf(outh_t[(size_t)k * 4000 + s], Wl[k], a);
    int r = s & 7;   // s % 8, replicating jnp.tile row indexing
#pragma unroll
    for (int k = 0; k < 8; ++k) a = fmaf(wth[(r * 12 + 11) * 8 + k], Wl[32 + k], a);
#pragma unroll
    for (int k = 0; k < 8; ++k) a = fmaf(ten[(r * 12 + 11) * 8 + k], Wl[40 + k], a);
    pred[s] = a;
}

extern "C" void kernel_launch(void* const* d_in, const int* in_sizes, int n_in,
                              void* d_out, int out_size, void* d_ws, size_t ws_size,
                              hipStream_t stream) {
    const float* x   = (const float*)d_in[0];
    const float* lat = (const float*)d_in[1];
    const float* lon = (const float*)d_in[2];
    const float* wth = (const float*)d_in[3];
    const float* ten = (const float*)d_in[4];
    const float* W1a = (const float*)d_in[5];
    const float* b1a = (const float*)d_in[6];
    const float* W1b = (const float*)d_in[7];
    const float* b1b = (const float*)d_in[8];
    const float* W2a = (const float*)d_in[9];
    const float* b2a = (const float*)d_in[10];
    const float* W2b = (const float*)d_in[11];
    const float* b2b = (const float*)d_in[12];
    const float* W3a = (const float*)d_in[13];
    const float* b3a = (const float*)d_in[14];
    const float* W3b = (const float*)d_in[15];
    const float* b3b = (const float*)d_in[16];
    const float* Wih = (const float*)d_in[17];
    const float* Whh = (const float*)d_in[18];
    const float* bih = (const float*)d_in[19];
    const float* bhh = (const float*)d_in[20];
    const float* Wl  = (const float*)d_in[21];
    const float* bl  = (const float*)d_in[22];

    float* ws = (float*)d_ws;
    float* feats0 = ws;                    // 12000
    float* h1     = ws + 12000;            // 128000 (4000*32)
    float* h2     = ws + 140000;           // 256000 (4000*64)
    float* h3     = ws + 396000;           // 32000  (4000*8)
    float* sqb    = ws + 428000;           // 4000
    float* ut     = ws + 432000;           // 512000 ([128][4000])
    float* outh   = ws + 944000;           // 128000 ([32][4000])
    int*   idx    = (int*)(ws + 1072000);  // 80000 ints
    float* pbuf   = ws + 1152000;          // 256000 (max layer: 4000*64)
    float* wdbuf  = ws + 1408000;          // 4160

    const int nb = (GN2 + 255) / 256;  // 16
    const int KB = GN2 / 4;            // 1000 blocks, one wave per point
    const int EB = 2000;               // edge-kernel grid (grid-stride over points)

    pack_feats<<<nb, 256, 0, stream>>>(x, lat, lon, feats0);
    prep_wd<<<1, 256, 0, stream>>>(W1a, W2a, W3a, wdbuf);

    // layer 1: 3 -> (6,12,32)
    sq_kernel<3><<<nb, 256, 0, stream>>>(feats0, sqb);
    knn_wave3<<<KB, 256, 0, stream>>>(feats0, sqb, idx);
    p_kernel<3, 12><<<(GN2 * 12 + 255) / 256, 256, 0, stream>>>(feats0, W1a, pbuf);
    edge_l1<<<EB, 64, 0, stream>>>(feats0, pbuf, wdbuf, W1b, b1a, b1b, idx, h1);

    // layer 2: 32 -> (64,64,64)
    sq_kernel<32><<<nb, 256, 0, stream>>>(h1, sqb);
    knn_wave4<8><<<KB, 256, 0, stream>>>(h1, sqb, idx);
    p_kernel<32, 64><<<(GN2 * 64 + 255) / 256, 256, 0, stream>>>(h1, W2a, pbuf);
    edge_l2<<<EB, 64, 0, stream>>>(h1, pbuf, wdbuf + 64, W2b, b2a, b2b, idx, h2);

    // layer 3: 64 -> (128,32,8)
    sq_kernel<64><<<nb, 256, 0, stream>>>(h2, sqb);
    knn_wave4<16><<<KB, 256, 0, stream>>>(h2, sqb, idx);
    p_kernel<64, 32><<<(GN2 * 32 + 255) / 256, 256, 0, stream>>>(h2, W3a, pbuf);
    edge_l3<<<EB, 64, 0, stream>>>(h2, pbuf, wdbuf + 2112, W3b, b3a, b3b, idx, h3);

    // LSTM (only batch column 11 matters)
    lstm_pre<<<(4000 * 128 + 255) / 256, 256, 0, stream>>>(h3, Wih, bih, bhh, ut);
    lstm_seq<<<1, 64, 0, stream>>>(ut, Whh, outh);

    final_pred<<<(4000 + 255) / 256, 256, 0, stream>>>(outh, wth, ten, Wl, bl, (float*)d_out);
}